// Round 1
// baseline (7232.101 us; speedup 1.0000x reference)
//
#include <hip/hip_runtime.h>
#include <math.h>

__device__ __forceinline__ float sigm(float x)  { return 1.f/(1.f+__expf(-x)); }
__device__ __forceinline__ float tanh_f(float x){ return 2.f/(1.f+__expf(-2.f*x)) - 1.f; }

// ---------------- upsample(2x, align_corners) + channel concat -> NHWC ----------------
// X0[n][h][w][c]: c<128 -> x2[n,c,h,w]; c>=128 -> bilinear-upsampled x1
__global__ __launch_bounds__(256) void k_upcat(const float* __restrict__ x1,
                                               const float* __restrict__ x2,
                                               float* __restrict__ X0) {
  int idx = blockIdx.x*256 + threadIdx.x;
  int c = idx & 255;
  int w = (idx >> 8) & 63;
  int h = (idx >> 14) & 63;
  int n = idx >> 20;
  float v;
  if (c < 128) {
    v = x2[((n*128 + c)*64 + h)*64 + w];
  } else {
    int cc = c - 128;
    float py = (h*31.0f)/63.0f;
    int ly = (int)py; int hy = min(ly+1, 31); float fy = py - (float)ly;
    float px = (w*31.0f)/63.0f;
    int lx = (int)px; int hx = min(lx+1, 31); float fx = px - (float)lx;
    const float* p = x1 + (size_t)(n*128 + cc)*1024;
    float v00 = p[ly*32+lx], v01 = p[ly*32+hx];
    float v10 = p[hy*32+lx], v11 = p[hy*32+hx];
    v = (1.f-fy)*((1.f-fx)*v00 + fx*v01) + fy*((1.f-fx)*v10 + fx*v11);
  }
  X0[idx] = v;
}

// ---------------- permute (B,H,W,256) -> (B,W,H,256); 1KB-block copy, coalesced both ways ----
__global__ __launch_bounds__(256) void k_transpose_hw(const float* __restrict__ src,
                                                      float* __restrict__ dst) {
  int p = blockIdx.x;                 // b*4096 + h*64 + w
  int b = p >> 12, h = (p >> 6) & 63, w = p & 63;
  int c = threadIdx.x;
  dst[(((b*64 + w)*64 + h) << 8) + c] = src[(p << 8) + c];
}

// ---------------- BiLSTM over (S=512, T=64, C=256) -> writes [dir*128, dir*128+128) ------
// 4 sequences per block, 512 threads (thread = gate), blockIdx.y = direction.
__global__ __launch_bounds__(512) void k_lstm(
    const float* __restrict__ X, float* __restrict__ Y,
    const float* __restrict__ Wih_f, const float* __restrict__ Whh_f,
    const float* __restrict__ bih_f, const float* __restrict__ bhh_f,
    const float* __restrict__ Wih_b, const float* __restrict__ Whh_b,
    const float* __restrict__ bih_b, const float* __restrict__ bhh_b) {
  int dir = blockIdx.y;
  const float* Wih = dir ? Wih_b : Wih_f;
  const float* Whh = dir ? Whh_b : Whh_f;
  const float* bi  = dir ? bih_b : bih_f;
  const float* bh  = dir ? bhh_b : bhh_f;
  int s0 = blockIdx.x * 4;
  __shared__ float xs[4][256];
  __shared__ float hs[4][128];
  __shared__ float gv[4][512];
  int t = threadIdx.x;                 // gate id 0..511 (i|f|g|o each 128)
  float bias = bi[t] + bh[t];
  const float* wi = Wih + t*256;
  const float* wh = Whh + t*128;
  int r_ = t >> 7, u_ = t & 127;       // (seq, hidden-unit) owned in update phase
  hs[r_][u_] = 0.f;
  float cst = 0.f;
  for (int step = 0; step < 64; ++step) {
    int tt = dir ? (63 - step) : step;
    // stage x_t for 4 seqs (1024 floats, 2 per thread, coalesced)
    {
      int i0 = t;
      ((float*)xs)[i0] = X[(size_t)(s0 + (i0>>8))*16384 + tt*256 + (i0 & 255)];
      int i1 = t + 512;
      ((float*)xs)[i1] = X[(size_t)(s0 + (i1>>8))*16384 + tt*256 + (i1 & 255)];
    }
    __syncthreads();                   // xs ready; hs(step-1) visible
    float a0 = bias, a1 = bias, a2 = bias, a3 = bias;
    #pragma unroll 4
    for (int c = 0; c < 256; c += 4) {
      float4 wv = *(const float4*)(wi + c);
      float4 p0 = *(const float4*)(&xs[0][c]);
      float4 p1 = *(const float4*)(&xs[1][c]);
      float4 p2 = *(const float4*)(&xs[2][c]);
      float4 p3 = *(const float4*)(&xs[3][c]);
      a0 = fmaf(wv.w,p0.w, fmaf(wv.z,p0.z, fmaf(wv.y,p0.y, fmaf(wv.x,p0.x, a0))));
      a1 = fmaf(wv.w,p1.w, fmaf(wv.z,p1.z, fmaf(wv.y,p1.y, fmaf(wv.x,p1.x, a1))));
      a2 = fmaf(wv.w,p2.w, fmaf(wv.z,p2.z, fmaf(wv.y,p2.y, fmaf(wv.x,p2.x, a2))));
      a3 = fmaf(wv.w,p3.w, fmaf(wv.z,p3.z, fmaf(wv.y,p3.y, fmaf(wv.x,p3.x, a3))));
    }
    #pragma unroll 4
    for (int u = 0; u < 128; u += 4) {
      float4 wv = *(const float4*)(wh + u);
      float4 p0 = *(const float4*)(&hs[0][u]);
      float4 p1 = *(const float4*)(&hs[1][u]);
      float4 p2 = *(const float4*)(&hs[2][u]);
      float4 p3 = *(const float4*)(&hs[3][u]);
      a0 = fmaf(wv.w,p0.w, fmaf(wv.z,p0.z, fmaf(wv.y,p0.y, fmaf(wv.x,p0.x, a0))));
      a1 = fmaf(wv.w,p1.w, fmaf(wv.z,p1.z, fmaf(wv.y,p1.y, fmaf(wv.x,p1.x, a1))));
      a2 = fmaf(wv.w,p2.w, fmaf(wv.z,p2.z, fmaf(wv.y,p2.y, fmaf(wv.x,p2.x, a2))));
      a3 = fmaf(wv.w,p3.w, fmaf(wv.z,p3.z, fmaf(wv.y,p3.y, fmaf(wv.x,p3.x, a3))));
    }
    gv[0][t] = a0; gv[1][t] = a1; gv[2][t] = a2; gv[3][t] = a3;
    __syncthreads();                   // gv ready
    {
      float iv = gv[r_][u_], fv = gv[r_][128+u_], gg = gv[r_][256+u_], ov = gv[r_][384+u_];
      cst = sigm(fv)*cst + sigm(iv)*tanh_f(gg);
      float hv = sigm(ov)*tanh_f(cst);
      hs[r_][u_] = hv;
      Y[(size_t)(s0+r_)*16384 + tt*256 + dir*128 + u_] = hv;
    }
  }
}

// ---------------- weight reformat OIHW -> (ky,kx,ci,co), optional channel fold -----------
__global__ __launch_bounds__(256) void k_wrefmt(const float* __restrict__ src,
                                                float* __restrict__ dst,
                                                int Ci, int Co, int fold) {
  int idx = blockIdx.x*256 + threadIdx.x;
  int total = 9*Ci*Co;
  if (idx >= total) return;
  int co = idx % Co;
  int rest = idx / Co;
  int ci = rest % Ci;
  int k  = rest / Ci;                 // ky*3+kx
  int CiS = fold ? Ci*2 : Ci;
  float v = src[(size_t)(co*CiS + ci)*9 + k];
  if (fold) v += src[(size_t)(co*CiS + ci + Ci)*9 + k];
  dst[idx] = v;
}

// ---------------- fused conv3x3 (SAME) + BN-scale + ReLU, NHWC implicit GEMM -------------
// block tile: 64 w x 64 co; thread: 4x4 register tile. Cin channels read from inA
// (and inB for ci>=256 when inB != null). wgt layout (3,3,Cin,Co).
__global__ __launch_bounds__(256) void k_conv3(
    const float* __restrict__ inA, const float* __restrict__ inB,
    const float* __restrict__ wgt,
    const float* __restrict__ gam, const float* __restrict__ bet,
    float* __restrict__ out, int Cin, int Co, int nchw) {
  __shared__ float si[64][69];        // [ci-chunk][wq] wq = w+kx in 0..65; pad 69 (stride%32=5)
  __shared__ float sw[64][64];        // [ci-chunk][co]
  int nh = blockIdx.x;                // n*64 + h
  int n = nh >> 6, h = nh & 63;
  int co0 = blockIdx.y << 6;
  int tid = threadIdx.x;
  int jj = tid & 15, ii = tid >> 4;   // co-sub, w-sub
  float acc[4][4];
  #pragma unroll
  for (int r = 0; r < 4; ++r)
    #pragma unroll
    for (int s = 0; s < 4; ++s) acc[r][s] = 0.f;

  int cs = inB ? 256 : Cin;           // channel stride of the input buffers
  for (int ky = 0; ky < 3; ++ky) {
    int ih = h + ky - 1;
    if (ih < 0 || ih > 63) continue;  // block-uniform
    for (int ci0 = 0; ci0 < Cin; ci0 += 64) {
      __syncthreads();                // previous tile fully consumed
      const float* src = inA; int cb = ci0;
      if (inB && ci0 >= 256) { src = inB; cb = ci0 - 256; }
      const float* srow = src + (size_t)((n*64 + ih)*64)*cs + cb;
      for (int idx = tid; idx < 66*64; idx += 256) {
        int wq = idx >> 6, cc = idx & 63;
        int iw = wq - 1;
        float v = 0.f;
        if (iw >= 0 && iw < 64) v = srow[(size_t)iw*cs + cc];
        si[cc][wq] = v;
      }
      for (int kx = 0; kx < 3; ++kx) {
        if (kx) __syncthreads();
        const float* wrow = wgt + (size_t)((ky*3+kx)*Cin + ci0)*Co + co0;
        for (int idx = tid; idx < 4096; idx += 256) {
          int cc = idx >> 6, co = idx & 63;
          sw[cc][co] = wrow[(size_t)cc*Co + co];
        }
        __syncthreads();
        #pragma unroll 4
        for (int cc = 0; cc < 64; ++cc) {
          float a0v = si[cc][ii      + kx];
          float a1v = si[cc][ii + 16 + kx];
          float a2v = si[cc][ii + 32 + kx];
          float a3v = si[cc][ii + 48 + kx];
          float b0 = sw[cc][jj], b1 = sw[cc][jj+16], b2 = sw[cc][jj+32], b3 = sw[cc][jj+48];
          acc[0][0]=fmaf(a0v,b0,acc[0][0]); acc[0][1]=fmaf(a0v,b1,acc[0][1]);
          acc[0][2]=fmaf(a0v,b2,acc[0][2]); acc[0][3]=fmaf(a0v,b3,acc[0][3]);
          acc[1][0]=fmaf(a1v,b0,acc[1][0]); acc[1][1]=fmaf(a1v,b1,acc[1][1]);
          acc[1][2]=fmaf(a1v,b2,acc[1][2]); acc[1][3]=fmaf(a1v,b3,acc[1][3]);
          acc[2][0]=fmaf(a2v,b0,acc[2][0]); acc[2][1]=fmaf(a2v,b1,acc[2][1]);
          acc[2][2]=fmaf(a2v,b2,acc[2][2]); acc[2][3]=fmaf(a2v,b3,acc[2][3]);
          acc[3][0]=fmaf(a3v,b0,acc[3][0]); acc[3][1]=fmaf(a3v,b1,acc[3][1]);
          acc[3][2]=fmaf(a3v,b2,acc[3][2]); acc[3][3]=fmaf(a3v,b3,acc[3][3]);
        }
      }
    }
  }
  const float kS = 0.9999950000374997f;   // 1/sqrt(1+1e-5)
  #pragma unroll
  for (int s = 0; s < 4; ++s) {
    int co = co0 + jj + 16*s;
    float scale = gam[co]*kS, bb = bet[co];
    #pragma unroll
    for (int r = 0; r < 4; ++r) {
      int w = ii + 16*r;
      float v = fmaf(acc[r][s], scale, bb);
      v = v > 0.f ? v : 0.f;
      if (nchw) out[(size_t)((n*Co + co)*64 + h)*64 + w] = v;
      else      out[(size_t)(nh*64 + w)*Co + co] = v;
    }
  }
}

extern "C" void kernel_launch(void* const* d_in, const int* in_sizes, int n_in,
                              void* d_out, int out_size, void* d_ws, size_t ws_size,
                              hipStream_t stream) {
  const float* x1    = (const float*)d_in[0];
  const float* x2    = (const float*)d_in[1];
  const float* Wih_f = (const float*)d_in[2];
  const float* Whh_f = (const float*)d_in[3];
  const float* bih_f = (const float*)d_in[4];
  const float* bhh_f = (const float*)d_in[5];
  const float* Wih_b = (const float*)d_in[6];
  const float* Whh_b = (const float*)d_in[7];
  const float* bih_b = (const float*)d_in[8];
  const float* bhh_b = (const float*)d_in[9];
  const float* c2_w1 = (const float*)d_in[10];
  const float* c2_g1 = (const float*)d_in[11];
  const float* c2_b1 = (const float*)d_in[12];
  const float* c2_w2 = (const float*)d_in[13];
  const float* c2_g2 = (const float*)d_in[14];
  const float* c2_b2 = (const float*)d_in[15];
  const float* cv_w1 = (const float*)d_in[16];
  const float* cv_g1 = (const float*)d_in[17];
  const float* cv_b1 = (const float*)d_in[18];
  const float* cv_w2 = (const float*)d_in[19];
  const float* cv_g2 = (const float*)d_in[20];
  const float* cv_b2 = (const float*)d_in[21];

  char* wsp = (char*)d_ws;
  const size_t SLOT = (size_t)8*64*64*256*4;      // 33.5 MB activation slot (NHWC)
  float* A = (float*)wsp; wsp += SLOT;
  float* B = (float*)wsp; wsp += SLOT;
  float* C = (float*)wsp; wsp += SLOT;
  float* w1f    = (float*)wsp; wsp += (size_t)9*256*256*4;  // folded c2_w1 (256-in)
  float* w1full = (float*)wsp; wsp += (size_t)9*512*256*4;  // c2_w1 (512-in)
  float* w2r    = (float*)wsp; wsp += (size_t)9*256*256*4;
  float* wv1    = (float*)wsp; wsp += (size_t)9*256*128*4;
  float* wv2    = (float*)wsp; wsp += (size_t)9*128*128*4;

  // weight prep
  k_wrefmt<<<(9*256*256+255)/256, 256, 0, stream>>>(c2_w1, w1f,    256, 256, 1);
  k_wrefmt<<<(9*512*256+255)/256, 256, 0, stream>>>(c2_w1, w1full, 512, 256, 0);
  k_wrefmt<<<(9*256*256+255)/256, 256, 0, stream>>>(c2_w2, w2r,    256, 256, 0);
  k_wrefmt<<<(9*256*128+255)/256, 256, 0, stream>>>(cv_w1, wv1,    256, 128, 0);
  k_wrefmt<<<(9*128*128+255)/256, 256, 0, stream>>>(cv_w2, wv2,    128, 128, 0);

  // upsample + concat -> A (NHWC, C=256)
  k_upcat<<<32768, 256, 0, stream>>>(x1, x2, A);
  // row BiLSTM: A (B*H, W, 256) -> B
  k_lstm<<<dim3(128,2), 512, 0, stream>>>(A, B, Wih_f, Whh_f, bih_f, bhh_f,
                                                Wih_b, Whh_b, bih_b, bhh_b);
  // (B,H,W,C) -> (B,W,H,C)
  k_transpose_hw<<<32768, 256, 0, stream>>>(B, C);
  // col BiLSTM: C (B*W, H, 256) -> A
  k_lstm<<<dim3(128,2), 512, 0, stream>>>(C, A, Wih_f, Whh_f, bih_f, bhh_f,
                                                Wih_b, Whh_b, bih_b, bhh_b);
  // back to (B,H,W,C): B = S (site output)
  k_transpose_hw<<<32768, 256, 0, stream>>>(A, B);

  // x_site = double_conv(concat([S,S])) with folded first conv
  k_conv3<<<dim3(512,4), 256, 0, stream>>>(B, nullptr, w1f, c2_g1, c2_b1, C, 256, 256, 0); // T1
  k_conv3<<<dim3(512,4), 256, 0, stream>>>(C, nullptr, w2r, c2_g2, c2_b2, A, 256, 256, 0); // XS
  // x = double_conv(concat([S, XS])) — two-pointer 512-in conv
  k_conv3<<<dim3(512,4), 256, 0, stream>>>(B, A, w1full, c2_g1, c2_b1, C, 512, 256, 0);    // T2
  k_conv3<<<dim3(512,4), 256, 0, stream>>>(C, nullptr, w2r, c2_g2, c2_b2, B, 256, 256, 0); // Y
  // final double_conv (cv), last conv writes NCHW straight to d_out
  k_conv3<<<dim3(512,2), 256, 0, stream>>>(B, nullptr, wv1, cv_g1, cv_b1, A, 256, 128, 0); // Z
  k_conv3<<<dim3(512,2), 256, 0, stream>>>(A, nullptr, wv2, cv_g2, cv_b2,
                                           (float*)d_out, 128, 128, 1);
}

// Round 2
// 3904.636 us; speedup vs baseline: 1.8522x; 1.8522x over previous
//
#include <hip/hip_runtime.h>
#include <hip/hip_bf16.h>
#include <math.h>

typedef __bf16 bf16x8 __attribute__((ext_vector_type(8)));
typedef float  f32x4  __attribute__((ext_vector_type(4)));

__device__ __forceinline__ float sigm(float x)  { return 1.f/(1.f+__expf(-x)); }
__device__ __forceinline__ float tanh_f(float x){ return 2.f/(1.f+__expf(-2.f*x)) - 1.f; }

// ---------------- upsample(2x, align_corners) + channel concat -> NHWC fp32 ----------------
__global__ __launch_bounds__(256) void k_upcat(const float* __restrict__ x1,
                                               const float* __restrict__ x2,
                                               float* __restrict__ X0) {
  int idx = blockIdx.x*256 + threadIdx.x;
  int c = idx & 255;
  int w = (idx >> 8) & 63;
  int h = (idx >> 14) & 63;
  int n = idx >> 20;
  float v;
  if (c < 128) {
    v = x2[((n*128 + c)*64 + h)*64 + w];
  } else {
    int cc = c - 128;
    float py = (h*31.0f)/63.0f;
    int ly = (int)py; int hy = min(ly+1, 31); float fy = py - (float)ly;
    float px = (w*31.0f)/63.0f;
    int lx = (int)px; int hx = min(lx+1, 31); float fx = px - (float)lx;
    const float* p = x1 + (size_t)(n*128 + cc)*1024;
    float v00 = p[ly*32+lx], v01 = p[ly*32+hx];
    float v10 = p[hy*32+lx], v11 = p[hy*32+hx];
    v = (1.f-fy)*((1.f-fx)*v00 + fx*v01) + fy*((1.f-fx)*v10 + fx*v11);
  }
  X0[idx] = v;
}

// ---------------- permute (B,H,W,256) -> (B,W,H,256) fp32 -------------------------------
__global__ __launch_bounds__(256) void k_transpose_hw(const float* __restrict__ src,
                                                      float* __restrict__ dst) {
  int p = blockIdx.x;                 // b*4096 + h*64 + w
  int b = p >> 12, h = (p >> 6) & 63, w = p & 63;
  int c = threadIdx.x;
  dst[(((b*64 + w)*64 + h) << 8) + c] = src[(p << 8) + c];
}

// ---------------- permute (B,W,H,256) fp32 -> (B,H,W,256) bf16 --------------------------
__global__ __launch_bounds__(256) void k_transpose_cvt(const float* __restrict__ src,
                                                       __hip_bfloat16* __restrict__ dst) {
  int p = blockIdx.x;                 // b*4096 + w*64 + h  (src index space)
  int b = p >> 12, w = (p >> 6) & 63, h = p & 63;
  int c = threadIdx.x;
  dst[(((b*64 + h)*64 + w) << 8) + c] = __float2bfloat16(src[(p << 8) + c]);
}

// ---------------- BiLSTM over (S=512, T=64, C=256), fp32 (unchanged, known-correct) -----
__global__ __launch_bounds__(512) void k_lstm(
    const float* __restrict__ X, float* __restrict__ Y,
    const float* __restrict__ Wih_f, const float* __restrict__ Whh_f,
    const float* __restrict__ bih_f, const float* __restrict__ bhh_f,
    const float* __restrict__ Wih_b, const float* __restrict__ Whh_b,
    const float* __restrict__ bih_b, const float* __restrict__ bhh_b) {
  int dir = blockIdx.y;
  const float* Wih = dir ? Wih_b : Wih_f;
  const float* Whh = dir ? Whh_b : Whh_f;
  const float* bi  = dir ? bih_b : bih_f;
  const float* bh  = dir ? bhh_b : bhh_f;
  int s0 = blockIdx.x * 4;
  __shared__ float xs[4][256];
  __shared__ float hs[4][128];
  __shared__ float gv[4][512];
  int t = threadIdx.x;
  float bias = bi[t] + bh[t];
  const float* wi = Wih + t*256;
  const float* wh = Whh + t*128;
  int r_ = t >> 7, u_ = t & 127;
  hs[r_][u_] = 0.f;
  float cst = 0.f;
  for (int step = 0; step < 64; ++step) {
    int tt = dir ? (63 - step) : step;
    {
      int i0 = t;
      ((float*)xs)[i0] = X[(size_t)(s0 + (i0>>8))*16384 + tt*256 + (i0 & 255)];
      int i1 = t + 512;
      ((float*)xs)[i1] = X[(size_t)(s0 + (i1>>8))*16384 + tt*256 + (i1 & 255)];
    }
    __syncthreads();
    float a0 = bias, a1 = bias, a2 = bias, a3 = bias;
    #pragma unroll 4
    for (int c = 0; c < 256; c += 4) {
      float4 wv = *(const float4*)(wi + c);
      float4 p0 = *(const float4*)(&xs[0][c]);
      float4 p1 = *(const float4*)(&xs[1][c]);
      float4 p2 = *(const float4*)(&xs[2][c]);
      float4 p3 = *(const float4*)(&xs[3][c]);
      a0 = fmaf(wv.w,p0.w, fmaf(wv.z,p0.z, fmaf(wv.y,p0.y, fmaf(wv.x,p0.x, a0))));
      a1 = fmaf(wv.w,p1.w, fmaf(wv.z,p1.z, fmaf(wv.y,p1.y, fmaf(wv.x,p1.x, a1))));
      a2 = fmaf(wv.w,p2.w, fmaf(wv.z,p2.z, fmaf(wv.y,p2.y, fmaf(wv.x,p2.x, a2))));
      a3 = fmaf(wv.w,p3.w, fmaf(wv.z,p3.z, fmaf(wv.y,p3.y, fmaf(wv.x,p3.x, a3))));
    }
    #pragma unroll 4
    for (int u = 0; u < 128; u += 4) {
      float4 wv = *(const float4*)(wh + u);
      float4 p0 = *(const float4*)(&hs[0][u]);
      float4 p1 = *(const float4*)(&hs[1][u]);
      float4 p2 = *(const float4*)(&hs[2][u]);
      float4 p3 = *(const float4*)(&hs[3][u]);
      a0 = fmaf(wv.w,p0.w, fmaf(wv.z,p0.z, fmaf(wv.y,p0.y, fmaf(wv.x,p0.x, a0))));
      a1 = fmaf(wv.w,p1.w, fmaf(wv.z,p1.z, fmaf(wv.y,p1.y, fmaf(wv.x,p1.x, a1))));
      a2 = fmaf(wv.w,p2.w, fmaf(wv.z,p2.z, fmaf(wv.y,p2.y, fmaf(wv.x,p2.x, a2))));
      a3 = fmaf(wv.w,p3.w, fmaf(wv.z,p3.z, fmaf(wv.y,p3.y, fmaf(wv.x,p3.x, a3))));
    }
    gv[0][t] = a0; gv[1][t] = a1; gv[2][t] = a2; gv[3][t] = a3;
    __syncthreads();
    {
      float iv = gv[r_][u_], fv = gv[r_][128+u_], gg = gv[r_][256+u_], ov = gv[r_][384+u_];
      cst = sigm(fv)*cst + sigm(iv)*tanh_f(gg);
      float hv = sigm(ov)*tanh_f(cst);
      hs[r_][u_] = hv;
      Y[(size_t)(s0+r_)*16384 + tt*256 + dir*128 + u_] = hv;
    }
  }
}

// ---------------- weight reformat OIHW fp32 -> (ky,kx,co,ci) bf16, optional fold ---------
__global__ __launch_bounds__(256) void k_wrefmt_bf16(const float* __restrict__ src,
                                                     __hip_bfloat16* __restrict__ dst,
                                                     int Ci, int Co, int fold) {
  int idx = blockIdx.x*256 + threadIdx.x;
  int total = 9*Ci*Co;
  if (idx >= total) return;
  int ci = idx % Ci;
  int co = (idx / Ci) % Co;
  int k  = idx / (Ci*Co);             // ky*3+kx
  int CiS = fold ? Ci*2 : Ci;
  float v = src[(size_t)(co*CiS + ci)*9 + k];
  if (fold) v += src[(size_t)(co*CiS + ci + Ci)*9 + k];
  dst[idx] = __float2bfloat16(v);
}

// ---------------- conv3x3 SAME + BN + ReLU, bf16 MFMA implicit GEMM ----------------------
// block: 2 h-rows x 64 w (M=128) x 128 co (N=128); 4 waves = 2x2 quadrants of 64x64.
// wgt layout (3,3,Co,Ci) bf16. Inputs bf16 NHWC. Output bf16 NHWC or fp32 NCHW.
__global__ __launch_bounds__(256) void k_conv3_mfma(
    const __hip_bfloat16* __restrict__ inA, const __hip_bfloat16* __restrict__ inB,
    const __hip_bfloat16* __restrict__ wgt,
    const float* __restrict__ gam, const float* __restrict__ bet,
    float* __restrict__ outF, __hip_bfloat16* __restrict__ outB,
    int Cin, int Co, int nchw) {
  __shared__ unsigned short si[2][66][72];   // [row][pixel(-1..64)][ci chunk], pad 64->72
  __shared__ unsigned short sw[128][72];     // [co][ci chunk]
  int bx = blockIdx.x;
  int n  = bx >> 5;
  int h0 = (bx & 31) << 1;
  int co0 = blockIdx.y << 7;
  int tid = threadIdx.x;
  int lane = tid & 63;
  int wid  = tid >> 6;
  int wm = wid >> 1;                   // which h-row
  int wn = wid & 1;                    // which co half
  int l15 = lane & 15, quad = lane >> 4;

  f32x4 acc[4][4];
  #pragma unroll
  for (int i = 0; i < 4; ++i)
    #pragma unroll
    for (int j = 0; j < 4; ++j) acc[i][j] = (f32x4){0.f,0.f,0.f,0.f};

  int cs = inB ? 256 : Cin;            // per-buffer channel stride
  for (int ky = 0; ky < 3; ++ky) {
    for (int ci0 = 0; ci0 < Cin; ci0 += 64) {
      const __hip_bfloat16* src = inA; int cb = ci0;
      if (inB && ci0 >= 256) { src = inB; cb = ci0 - 256; }
      __syncthreads();                 // protect si (+ last sw) from previous use
      // stage 2 rows x 66 pixels x 64 ci (ushort4 = 4 bf16)
      for (int idx = tid; idx < 2112; idx += 256) {
        int r   = idx >= 1056;
        int rem = idx - (r << 10) - (r << 5);   // idx - r*1056
        int p   = rem >> 4;
        int c4  = (rem & 15) << 2;
        int ih  = h0 + r + ky - 1;
        int iw  = p - 1;
        ushort4 v = {0,0,0,0};
        if (ih >= 0 && ih <= 63 && iw >= 0 && iw <= 63)
          v = *(const ushort4*)((const unsigned short*)src +
                (size_t)((n*64 + ih)*64 + iw)*cs + cb + c4);
        *(ushort4*)&si[r][p][c4] = v;
      }
      for (int kx = 0; kx < 3; ++kx) {
        __syncthreads();               // si ready (kx=0) / protect sw (kx>0)
        const unsigned short* wsrc = (const unsigned short*)wgt +
            (size_t)((ky*3 + kx)*Co + co0)*Cin + ci0;
        for (int idx = tid; idx < 2048; idx += 256) {
          int co = idx >> 4;
          int c4 = (idx & 15) << 2;
          *(ushort4*)&sw[co][c4] = *(const ushort4*)(wsrc + (size_t)co*Cin + c4);
        }
        __syncthreads();
        #pragma unroll
        for (int k0 = 0; k0 < 64; k0 += 32) {
          bf16x8 af[4], bfr[4];
          #pragma unroll
          for (int mt = 0; mt < 4; ++mt) {
            int p = mt*16 + l15 + kx;
            af[mt] = *(const bf16x8*)&si[wm][p][k0 + quad*8];
          }
          #pragma unroll
          for (int nt = 0; nt < 4; ++nt) {
            int co = wn*64 + nt*16 + l15;
            bfr[nt] = *(const bf16x8*)&sw[co][k0 + quad*8];
          }
          #pragma unroll
          for (int mt = 0; mt < 4; ++mt)
            #pragma unroll
            for (int nt = 0; nt < 4; ++nt)
              acc[mt][nt] = __builtin_amdgcn_mfma_f32_16x16x32_bf16(
                  af[mt], bfr[nt], acc[mt][nt], 0, 0, 0);
        }
      }
    }
  }
  // epilogue: BN scale + ReLU; C/D layout col=lane&15, row=quad*4+reg
  const float kS = 0.9999950000374997f;   // 1/sqrt(1+1e-5)
  int h = h0 + wm;
  #pragma unroll
  for (int nt = 0; nt < 4; ++nt) {
    int co = co0 + wn*64 + nt*16 + l15;
    float scale = gam[co]*kS, bb = bet[co];
    #pragma unroll
    for (int mt = 0; mt < 4; ++mt) {
      f32x4 a = acc[mt][nt];
      #pragma unroll
      for (int r = 0; r < 4; ++r) {
        int w = mt*16 + quad*4 + r;
        float v = fmaf(a[r], scale, bb);
        v = v > 0.f ? v : 0.f;
        if (nchw) outF[(size_t)((n*Co + co)*64 + h)*64 + w] = v;
        else      outB[(size_t)((n*64 + h)*64 + w)*Co + co] = __float2bfloat16(v);
      }
    }
  }
}

extern "C" void kernel_launch(void* const* d_in, const int* in_sizes, int n_in,
                              void* d_out, int out_size, void* d_ws, size_t ws_size,
                              hipStream_t stream) {
  const float* x1    = (const float*)d_in[0];
  const float* x2    = (const float*)d_in[1];
  const float* Wih_f = (const float*)d_in[2];
  const float* Whh_f = (const float*)d_in[3];
  const float* bih_f = (const float*)d_in[4];
  const float* bhh_f = (const float*)d_in[5];
  const float* Wih_b = (const float*)d_in[6];
  const float* Whh_b = (const float*)d_in[7];
  const float* bih_b = (const float*)d_in[8];
  const float* bhh_b = (const float*)d_in[9];
  const float* c2_w1 = (const float*)d_in[10];
  const float* c2_g1 = (const float*)d_in[11];
  const float* c2_b1 = (const float*)d_in[12];
  const float* c2_w2 = (const float*)d_in[13];
  const float* c2_g2 = (const float*)d_in[14];
  const float* c2_b2 = (const float*)d_in[15];
  const float* cv_w1 = (const float*)d_in[16];
  const float* cv_g1 = (const float*)d_in[17];
  const float* cv_b1 = (const float*)d_in[18];
  const float* cv_w2 = (const float*)d_in[19];
  const float* cv_g2 = (const float*)d_in[20];
  const float* cv_b2 = (const float*)d_in[21];

  char* wsp = (char*)d_ws;
  const size_t SLOT = (size_t)8*64*64*256*4;      // 33.5 MB fp32 activation slot
  float* A = (float*)(wsp + 0*SLOT);              // X0, later colOut
  float* B = (float*)(wsp + 1*SLOT);              // rowOut; later bf16 D1/D2
  float* C = (float*)(wsp + 2*SLOT);              // rowOut^T; later bf16 Sb
  __hip_bfloat16* Sb = (__hip_bfloat16*)(wsp + 2*SLOT);
  __hip_bfloat16* D1 = (__hip_bfloat16*)(wsp + 1*SLOT);
  __hip_bfloat16* D2 = (__hip_bfloat16*)(wsp + 1*SLOT + SLOT/2);
  char* wq = wsp + 3*SLOT;
  __hip_bfloat16* w1f    = (__hip_bfloat16*)(wq);                 // folded c2_w1 (256-in)
  __hip_bfloat16* w1full = (__hip_bfloat16*)(wq + 1179648);       // c2_w1 (512-in)
  __hip_bfloat16* w2r    = (__hip_bfloat16*)(wq + 1179648 + 2359296);
  __hip_bfloat16* wv1    = (__hip_bfloat16*)(wq + 2*1179648 + 2359296);
  __hip_bfloat16* wv2    = (__hip_bfloat16*)(wq + 2*1179648 + 2359296 + 589824);

  // weight prep -> bf16 (3,3,Co,Ci)
  k_wrefmt_bf16<<<(9*256*256+255)/256, 256, 0, stream>>>(c2_w1, w1f,    256, 256, 1);
  k_wrefmt_bf16<<<(9*512*256+255)/256, 256, 0, stream>>>(c2_w1, w1full, 512, 256, 0);
  k_wrefmt_bf16<<<(9*256*256+255)/256, 256, 0, stream>>>(c2_w2, w2r,    256, 256, 0);
  k_wrefmt_bf16<<<(9*256*128+255)/256, 256, 0, stream>>>(cv_w1, wv1,    256, 128, 0);
  k_wrefmt_bf16<<<(9*128*128+255)/256, 256, 0, stream>>>(cv_w2, wv2,    128, 128, 0);

  // upsample + concat -> A (NHWC fp32)
  k_upcat<<<32768, 256, 0, stream>>>(x1, x2, A);
  // row BiLSTM: A (B*H, W, 256) -> B
  k_lstm<<<dim3(128,2), 512, 0, stream>>>(A, B, Wih_f, Whh_f, bih_f, bhh_f,
                                                Wih_b, Whh_b, bih_b, bhh_b);
  // (B,H,W,C) -> (B,W,H,C)
  k_transpose_hw<<<32768, 256, 0, stream>>>(B, C);
  // col BiLSTM: C -> A
  k_lstm<<<dim3(128,2), 512, 0, stream>>>(C, A, Wih_f, Whh_f, bih_f, bhh_f,
                                                Wih_b, Whh_b, bih_b, bhh_b);
  // (B,W,H,C) fp32 -> (B,H,W,C) bf16 = S
  k_transpose_cvt<<<32768, 256, 0, stream>>>(A, Sb);

  // x_site = double_conv(concat([S,S])) with folded first conv
  k_conv3_mfma<<<dim3(256,2), 256, 0, stream>>>(Sb, nullptr, w1f, c2_g1, c2_b1,
                                                nullptr, D1, 256, 256, 0);      // T1
  k_conv3_mfma<<<dim3(256,2), 256, 0, stream>>>(D1, nullptr, w2r, c2_g2, c2_b2,
                                                nullptr, D2, 256, 256, 0);      // XS
  // x = double_conv(concat([S, XS]))
  k_conv3_mfma<<<dim3(256,2), 256, 0, stream>>>(Sb, D2, w1full, c2_g1, c2_b1,
                                                nullptr, D1, 512, 256, 0);      // T2
  k_conv3_mfma<<<dim3(256,2), 256, 0, stream>>>(D1, nullptr, w2r, c2_g2, c2_b2,
                                                nullptr, D2, 256, 256, 0);      // Y
  // final double_conv (cv); last conv writes fp32 NCHW to d_out
  k_conv3_mfma<<<dim3(256,1), 256, 0, stream>>>(D2, nullptr, wv1, cv_g1, cv_b1,
                                                nullptr, D1, 256, 128, 0);      // Z
  k_conv3_mfma<<<dim3(256,1), 256, 0, stream>>>(D1, nullptr, wv2, cv_g2, cv_b2,
                                                (float*)d_out, nullptr, 128, 128, 1);
}

// Round 3
// 1659.745 us; speedup vs baseline: 4.3574x; 2.3526x over previous
//
#include <hip/hip_runtime.h>
#include <hip/hip_bf16.h>
#include <math.h>

typedef __bf16 bf16x8 __attribute__((ext_vector_type(8)));
typedef float  f32x4  __attribute__((ext_vector_type(4)));

__device__ __forceinline__ float sigm(float x)  { return 1.f/(1.f+__expf(-x)); }
__device__ __forceinline__ float tanh_f(float x){ return 2.f/(1.f+__expf(-2.f*x)) - 1.f; }
__device__ __forceinline__ float b2f(unsigned short u){
  unsigned int x = ((unsigned int)u) << 16; return __uint_as_float(x);
}
__device__ __forceinline__ unsigned short f2b(float v){
  __hip_bfloat16 h = __float2bfloat16(v); return *(unsigned short*)&h;
}

// ---------------- upsample(2x, align_corners) + channel concat -> NHWC bf16 --------------
__global__ __launch_bounds__(256) void k_upcat(const float* __restrict__ x1,
                                               const float* __restrict__ x2,
                                               __hip_bfloat16* __restrict__ X0) {
  int idx = blockIdx.x*256 + threadIdx.x;
  int c = idx & 255;
  int w = (idx >> 8) & 63;
  int h = (idx >> 14) & 63;
  int n = idx >> 20;
  float v;
  if (c < 128) {
    v = x2[((n*128 + c)*64 + h)*64 + w];
  } else {
    int cc = c - 128;
    float py = (h*31.0f)/63.0f;
    int ly = (int)py; int hy = min(ly+1, 31); float fy = py - (float)ly;
    float px = (w*31.0f)/63.0f;
    int lx = (int)px; int hx = min(lx+1, 31); float fx = px - (float)lx;
    const float* p = x1 + (size_t)(n*128 + cc)*1024;
    float v00 = p[ly*32+lx], v01 = p[ly*32+hx];
    float v10 = p[hy*32+lx], v11 = p[hy*32+hx];
    v = (1.f-fy)*((1.f-fx)*v00 + fx*v01) + fy*((1.f-fx)*v10 + fx*v11);
  }
  X0[idx] = __float2bfloat16(v);
}

// ---------------- Wih concat -> bf16 [1024][256]; biasc[1024] = bih+bhh ------------------
__global__ __launch_bounds__(256) void k_wih_prep(
    const float* __restrict__ Wf, const float* __restrict__ Wb,
    const float* __restrict__ bif, const float* __restrict__ bhf,
    const float* __restrict__ bib, const float* __restrict__ bhb,
    __hip_bfloat16* __restrict__ wihc, float* __restrict__ biasc) {
  int idx = blockIdx.x*256 + threadIdx.x;     // 1024*256
  int n = idx >> 8, k = idx & 255;
  float v = (n < 512) ? Wf[n*256 + k] : Wb[(n-512)*256 + k];
  wihc[idx] = __float2bfloat16(v);
  if (idx < 1024) biasc[idx] = (idx < 512) ? bif[idx] + bhf[idx]
                                           : bib[idx-512] + bhb[idx-512];
}

// ---------------- xg GEMM: xg[dir][t][seq][gate] (fragment-swizzled bf16) ----------------
// A: Xin [seq*64+t][256] bf16 (row-gathered so an m-tile = 16 seqs at fixed t).
// B: wihc [n=dir*512+gate][k]. M-block 128 seqs at fixed t, N-block 128 gates.
// Output tile (16x16) stored as [tile][lane][4] so the recurrent kernel reads ushort4.
__global__ __launch_bounds__(256) void k_xg_gemm(
    const __hip_bfloat16* __restrict__ Xin,
    const __hip_bfloat16* __restrict__ Wihc,
    const float* __restrict__ biasc,
    __hip_bfloat16* __restrict__ xg) {
  __shared__ __align__(16) unsigned short sa[128][72];
  __shared__ __align__(16) unsigned short sw[128][72];
  int bx = blockIdx.x;                 // 256: t = bx>>2, seq0 = (bx&3)*128
  int t = bx >> 2, seq0 = (bx & 3) << 7;
  int n0 = blockIdx.y << 7;
  int tid = threadIdx.x, lane = tid & 63, wid = tid >> 6;
  int wm = wid >> 1, wn = wid & 1;
  int l15 = lane & 15, quad = lane >> 4;
  f32x4 acc[4][4];
  #pragma unroll
  for (int i = 0; i < 4; ++i)
    #pragma unroll
    for (int j = 0; j < 4; ++j) acc[i][j] = (f32x4){0.f,0.f,0.f,0.f};

  for (int k0 = 0; k0 < 256; k0 += 64) {
    __syncthreads();
    for (int idx = tid; idx < 2048; idx += 256) {
      int row = idx >> 4, c4 = (idx & 15) << 2;
      *(ushort4*)&sa[row][c4] = *(const ushort4*)((const unsigned short*)Xin +
          (size_t)((seq0 + row)*64 + t)*256 + k0 + c4);
      *(ushort4*)&sw[row][c4] = *(const ushort4*)((const unsigned short*)Wihc +
          (size_t)(n0 + row)*256 + k0 + c4);
    }
    __syncthreads();
    #pragma unroll
    for (int k32 = 0; k32 < 64; k32 += 32) {
      bf16x8 af[4], bfr[4];
      #pragma unroll
      for (int mt = 0; mt < 4; ++mt)
        af[mt] = *(const bf16x8*)&sa[wm*64 + mt*16 + l15][k32 + quad*8];
      #pragma unroll
      for (int nt = 0; nt < 4; ++nt)
        bfr[nt] = *(const bf16x8*)&sw[wn*64 + nt*16 + l15][k32 + quad*8];
      #pragma unroll
      for (int mt = 0; mt < 4; ++mt)
        #pragma unroll
        for (int nt = 0; nt < 4; ++nt)
          acc[mt][nt] = __builtin_amdgcn_mfma_f32_16x16x32_bf16(
              af[mt], bfr[nt], acc[mt][nt], 0, 0, 0);
    }
  }
  // epilogue: + bias, bf16, fragment-order store (512B contiguous per tile per wave)
  #pragma unroll
  for (int nt = 0; nt < 4; ++nt) {
    int n_g = n0 + wn*64 + nt*16;             // tile col base (gate dim incl dir)
    int dir = n_g >> 9;
    int gtile = (n_g & 511) >> 4;
    float bias = biasc[n_g + l15];
    #pragma unroll
    for (int mt = 0; mt < 4; ++mt) {
      int seq_tile = (seq0 + wm*64 + mt*16) >> 4;
      size_t base = ((size_t)(dir*64 + t)*1024 + seq_tile*32 + gtile)*256 + lane*4;
      f32x4 a = acc[mt][nt];
      ushort4 o;
      o.x = f2b(a[0] + bias); o.y = f2b(a[1] + bias);
      o.z = f2b(a[2] + bias); o.w = f2b(a[3] + bias);
      *(ushort4*)((unsigned short*)xg + base) = o;
    }
  }
}

// ---------------- recurrent LSTM core: 32 seqs/block, Whh in VGPRs, h in LDS -------------
// grid (16, 2). Writes h (bf16) to out at ((b*64+t)*64 + s&63)*256 + dir*128 + unit,
// which is the transposed layout the NEXT stage wants (pass1->RT, pass2->Sb).
__global__ __launch_bounds__(256, 1) void k_lstm_rec(
    const __hip_bfloat16* __restrict__ xg,
    const float* __restrict__ WhhF, const float* __restrict__ WhhB,
    __hip_bfloat16* __restrict__ out) {
  const int dir = blockIdx.y;
  const int sb  = blockIdx.x;               // seqs sb*32 .. +32
  const float* Whh = dir ? WhhB : WhhF;
  __shared__ __align__(16) unsigned short hs[32][136];   // [seq][unit], pad 128->136
  const int tid = threadIdx.x, lane = tid & 63, wv = tid >> 6;
  const int l15 = lane & 15, quad = lane >> 4;

  // Whh fragments in registers: wf[g][ut][kc]; gate = g*128 + wv*32 + ut*16 + l15
  bf16x8 wf[4][2][4];
  #pragma unroll
  for (int g = 0; g < 4; ++g)
    #pragma unroll
    for (int ut = 0; ut < 2; ++ut) {
      int gate = g*128 + wv*32 + ut*16 + l15;
      #pragma unroll
      for (int kc = 0; kc < 4; ++kc) {
        const float* wp = Whh + (size_t)gate*128 + kc*32 + quad*8;
        float4 w0 = *(const float4*)wp;
        float4 w1 = *(const float4*)(wp + 4);
        bf16x8 f;
        f[0]=(__bf16)w0.x; f[1]=(__bf16)w0.y; f[2]=(__bf16)w0.z; f[3]=(__bf16)w0.w;
        f[4]=(__bf16)w1.x; f[5]=(__bf16)w1.y; f[6]=(__bf16)w1.z; f[7]=(__bf16)w1.w;
        wf[g][ut][kc] = f;
      }
    }
  for (int i = tid; i < 32*136; i += 256) ((unsigned short*)hs)[i] = 0;

  float cst[2][2][4];
  #pragma unroll
  for (int mt = 0; mt < 2; ++mt)
    #pragma unroll
    for (int ut = 0; ut < 2; ++ut)
      #pragma unroll
      for (int r = 0; r < 4; ++r) cst[mt][ut][r] = 0.f;

  const unsigned short* xbase = (const unsigned short*)xg +
      (size_t)dir*64*262144 + lane*4;
  ushort4 xv[2][4][2], xn[2][4][2];
  {
    int t0 = dir ? 63 : 0;
    #pragma unroll
    for (int mt = 0; mt < 2; ++mt)
      #pragma unroll
      for (int g = 0; g < 4; ++g)
        #pragma unroll
        for (int ut = 0; ut < 2; ++ut)
          xv[mt][g][ut] = *(const ushort4*)(xbase +
              ((size_t)t0*1024 + (sb*2 + mt)*32 + g*8 + wv*2 + ut)*256);
  }
  __syncthreads();

  for (int step = 0; step < 64; ++step) {
    int t = dir ? 63 - step : step;
    bf16x8 af[2][4];
    #pragma unroll
    for (int mt = 0; mt < 2; ++mt)
      #pragma unroll
      for (int kc = 0; kc < 4; ++kc)
        af[mt][kc] = *(const bf16x8*)&hs[mt*16 + l15][kc*32 + quad*8];
    f32x4 acc[2][4][2];
    #pragma unroll
    for (int mt = 0; mt < 2; ++mt)
      #pragma unroll
      for (int g = 0; g < 4; ++g)
        #pragma unroll
        for (int ut = 0; ut < 2; ++ut) acc[mt][g][ut] = (f32x4){0.f,0.f,0.f,0.f};
    #pragma unroll
    for (int kc = 0; kc < 4; ++kc)
      #pragma unroll
      for (int mt = 0; mt < 2; ++mt)
        #pragma unroll
        for (int g = 0; g < 4; ++g)
          #pragma unroll
          for (int ut = 0; ut < 2; ++ut)
            acc[mt][g][ut] = __builtin_amdgcn_mfma_f32_16x16x32_bf16(
                af[mt][kc], wf[g][ut][kc], acc[mt][g][ut], 0, 0, 0);
    // prefetch next step's xg tiles
    {
      int ts = step + 1 < 64 ? step + 1 : 63;
      int tn = dir ? 63 - ts : ts;
      #pragma unroll
      for (int mt = 0; mt < 2; ++mt)
        #pragma unroll
        for (int g = 0; g < 4; ++g)
          #pragma unroll
          for (int ut = 0; ut < 2; ++ut)
            xn[mt][g][ut] = *(const ushort4*)(xbase +
                ((size_t)tn*1024 + (sb*2 + mt)*32 + g*8 + wv*2 + ut)*256);
    }
    __syncthreads();                   // all waves done reading hs
    #pragma unroll
    for (int mt = 0; mt < 2; ++mt)
      #pragma unroll
      for (int ut = 0; ut < 2; ++ut) {
        const unsigned short* xi = (const unsigned short*)&xv[mt][0][ut];
        const unsigned short* xf = (const unsigned short*)&xv[mt][1][ut];
        const unsigned short* xgg= (const unsigned short*)&xv[mt][2][ut];
        const unsigned short* xo = (const unsigned short*)&xv[mt][3][ut];
        #pragma unroll
        for (int r = 0; r < 4; ++r) {
          float I = acc[mt][0][ut][r] + b2f(xi[r]);
          float F = acc[mt][1][ut][r] + b2f(xf[r]);
          float G = acc[mt][2][ut][r] + b2f(xgg[r]);
          float O = acc[mt][3][ut][r] + b2f(xo[r]);
          float cv = sigm(F)*cst[mt][ut][r] + sigm(I)*tanh_f(G);
          float hv = sigm(O)*tanh_f(cv);
          cst[mt][ut][r] = cv;
          unsigned short hb = f2b(hv);
          hs[mt*16 + quad*4 + r][wv*32 + ut*16 + l15] = hb;
          int s = sb*32 + mt*16 + quad*4 + r;
          size_t oa = (size_t)(((s >> 6)*64 + t)*64 + (s & 63))*256
                      + dir*128 + wv*32 + ut*16 + l15;
          ((unsigned short*)out)[oa] = hb;
        }
      }
    #pragma unroll
    for (int mt = 0; mt < 2; ++mt)
      #pragma unroll
      for (int g = 0; g < 4; ++g)
        #pragma unroll
        for (int ut = 0; ut < 2; ++ut) xv[mt][g][ut] = xn[mt][g][ut];
    __syncthreads();                   // hs ready for next step
  }
}

// ---------------- weight reformat OIHW fp32 -> (ky,kx,co,ci) bf16, optional fold ---------
__global__ __launch_bounds__(256) void k_wrefmt_bf16(const float* __restrict__ src,
                                                     __hip_bfloat16* __restrict__ dst,
                                                     int Ci, int Co, int fold) {
  int idx = blockIdx.x*256 + threadIdx.x;
  int total = 9*Ci*Co;
  if (idx >= total) return;
  int ci = idx % Ci;
  int co = (idx / Ci) % Co;
  int k  = idx / (Ci*Co);             // ky*3+kx
  int CiS = fold ? Ci*2 : Ci;
  float v = src[(size_t)(co*CiS + ci)*9 + k];
  if (fold) v += src[(size_t)(co*CiS + ci + Ci)*9 + k];
  dst[idx] = __float2bfloat16(v);
}

// ---------------- conv3x3 SAME + BN + ReLU, bf16 MFMA implicit GEMM ----------------------
__global__ __launch_bounds__(256) void k_conv3_mfma(
    const __hip_bfloat16* __restrict__ inA, const __hip_bfloat16* __restrict__ inB,
    const __hip_bfloat16* __restrict__ wgt,
    const float* __restrict__ gam, const float* __restrict__ bet,
    float* __restrict__ outF, __hip_bfloat16* __restrict__ outB,
    int Cin, int Co, int nchw) {
  __shared__ unsigned short si[2][66][72];   // [row][pixel(-1..64)][ci chunk]
  __shared__ unsigned short sw[128][72];     // [co][ci chunk]
  int bx = blockIdx.x;
  int n  = bx >> 5;
  int h0 = (bx & 31) << 1;
  int co0 = blockIdx.y << 7;
  int tid = threadIdx.x;
  int lane = tid & 63;
  int wid  = tid >> 6;
  int wm = wid >> 1;
  int wn = wid & 1;
  int l15 = lane & 15, quad = lane >> 4;

  f32x4 acc[4][4];
  #pragma unroll
  for (int i = 0; i < 4; ++i)
    #pragma unroll
    for (int j = 0; j < 4; ++j) acc[i][j] = (f32x4){0.f,0.f,0.f,0.f};

  int cs = inB ? 256 : Cin;
  for (int ky = 0; ky < 3; ++ky) {
    for (int ci0 = 0; ci0 < Cin; ci0 += 64) {
      const __hip_bfloat16* src = inA; int cb = ci0;
      if (inB && ci0 >= 256) { src = inB; cb = ci0 - 256; }
      __syncthreads();
      for (int idx = tid; idx < 2112; idx += 256) {
        int r   = idx >= 1056;
        int rem = idx - (r << 10) - (r << 5);
        int p   = rem >> 4;
        int c4  = (rem & 15) << 2;
        int ih  = h0 + r + ky - 1;
        int iw  = p - 1;
        ushort4 v = {0,0,0,0};
        if (ih >= 0 && ih <= 63 && iw >= 0 && iw <= 63)
          v = *(const ushort4*)((const unsigned short*)src +
                (size_t)((n*64 + ih)*64 + iw)*cs + cb + c4);
        *(ushort4*)&si[r][p][c4] = v;
      }
      for (int kx = 0; kx < 3; ++kx) {
        __syncthreads();
        const unsigned short* wsrc = (const unsigned short*)wgt +
            (size_t)((ky*3 + kx)*Co + co0)*Cin + ci0;
        for (int idx = tid; idx < 2048; idx += 256) {
          int co = idx >> 4;
          int c4 = (idx & 15) << 2;
          *(ushort4*)&sw[co][c4] = *(const ushort4*)(wsrc + (size_t)co*Cin + c4);
        }
        __syncthreads();
        #pragma unroll
        for (int k0 = 0; k0 < 64; k0 += 32) {
          bf16x8 af[4], bfr[4];
          #pragma unroll
          for (int mt = 0; mt < 4; ++mt) {
            int p = mt*16 + l15 + kx;
            af[mt] = *(const bf16x8*)&si[wm][p][k0 + quad*8];
          }
          #pragma unroll
          for (int nt = 0; nt < 4; ++nt) {
            int co = wn*64 + nt*16 + l15;
            bfr[nt] = *(const bf16x8*)&sw[co][k0 + quad*8];
          }
          #pragma unroll
          for (int mt = 0; mt < 4; ++mt)
            #pragma unroll
            for (int nt = 0; nt < 4; ++nt)
              acc[mt][nt] = __builtin_amdgcn_mfma_f32_16x16x32_bf16(
                  af[mt], bfr[nt], acc[mt][nt], 0, 0, 0);
        }
      }
    }
  }
  const float kS = 0.9999950000374997f;   // 1/sqrt(1+1e-5)
  int h = h0 + wm;
  #pragma unroll
  for (int nt = 0; nt < 4; ++nt) {
    int co = co0 + wn*64 + nt*16 + l15;
    float scale = gam[co]*kS, bb = bet[co];
    #pragma unroll
    for (int mt = 0; mt < 4; ++mt) {
      f32x4 a = acc[mt][nt];
      #pragma unroll
      for (int r = 0; r < 4; ++r) {
        int w = mt*16 + quad*4 + r;
        float v = fmaf(a[r], scale, bb);
        v = v > 0.f ? v : 0.f;
        if (nchw) outF[(size_t)((n*Co + co)*64 + h)*64 + w] = v;
        else      outB[(size_t)((n*64 + h)*64 + w)*Co + co] = __float2bfloat16(v);
      }
    }
  }
}

extern "C" void kernel_launch(void* const* d_in, const int* in_sizes, int n_in,
                              void* d_out, int out_size, void* d_ws, size_t ws_size,
                              hipStream_t stream) {
  const float* x1    = (const float*)d_in[0];
  const float* x2    = (const float*)d_in[1];
  const float* Wih_f = (const float*)d_in[2];
  const float* Whh_f = (const float*)d_in[3];
  const float* bih_f = (const float*)d_in[4];
  const float* bhh_f = (const float*)d_in[5];
  const float* Wih_b = (const float*)d_in[6];
  const float* Whh_b = (const float*)d_in[7];
  const float* bih_b = (const float*)d_in[8];
  const float* bhh_b = (const float*)d_in[9];
  const float* c2_w1 = (const float*)d_in[10];
  const float* c2_g1 = (const float*)d_in[11];
  const float* c2_b1 = (const float*)d_in[12];
  const float* c2_w2 = (const float*)d_in[13];
  const float* c2_g2 = (const float*)d_in[14];
  const float* c2_b2 = (const float*)d_in[15];
  const float* cv_w1 = (const float*)d_in[16];
  const float* cv_g1 = (const float*)d_in[17];
  const float* cv_b1 = (const float*)d_in[18];
  const float* cv_w2 = (const float*)d_in[19];
  const float* cv_g2 = (const float*)d_in[20];
  const float* cv_b2 = (const float*)d_in[21];

  // ---- workspace layout (~107 MB, aliased) ----
  char* base = (char*)d_ws;
  const size_t SLOTB = 16777216ull;                 // bf16 activation slot (8*64*64*256*2)
  __hip_bfloat16* Xb  = (__hip_bfloat16*)(base);                    // dead after GEMM-1
  __hip_bfloat16* Sb  = (__hip_bfloat16*)(base);                    // site output (pass-2)
  __hip_bfloat16* XG  = (__hip_bfloat16*)(base + SLOTB);            // 67 MB, dead after rec-2
  __hip_bfloat16* D2  = (__hip_bfloat16*)(base + SLOTB);            // aliases XG
  __hip_bfloat16* D2b = (__hip_bfloat16*)(base + 2*SLOTB);          // aliases XG+16.8MB
  __hip_bfloat16* RT  = (__hip_bfloat16*)(base + SLOTB + 67108864ull); // dead after GEMM-2
  __hip_bfloat16* D1  = RT;
  char* wq = base + SLOTB + 67108864ull + SLOTB;    // +100663296
  __hip_bfloat16* wihc  = (__hip_bfloat16*)wq;                      // 512 KB
  float*          biasc = (float*)(wq + 524288);                    // 4 KB
  char* cw = wq + 528384;
  __hip_bfloat16* w1f    = (__hip_bfloat16*)(cw);
  __hip_bfloat16* w1full = (__hip_bfloat16*)(cw + 1179648);
  __hip_bfloat16* w2r    = (__hip_bfloat16*)(cw + 3538944);
  __hip_bfloat16* wv1    = (__hip_bfloat16*)(cw + 4718592);
  __hip_bfloat16* wv2    = (__hip_bfloat16*)(cw + 5308416);

  // weight prep
  k_wih_prep<<<1024, 256, 0, stream>>>(Wih_f, Wih_b, bih_f, bhh_f, bih_b, bhh_b,
                                       wihc, biasc);
  k_wrefmt_bf16<<<(9*256*256+255)/256, 256, 0, stream>>>(c2_w1, w1f,    256, 256, 1);
  k_wrefmt_bf16<<<(9*512*256+255)/256, 256, 0, stream>>>(c2_w1, w1full, 512, 256, 0);
  k_wrefmt_bf16<<<(9*256*256+255)/256, 256, 0, stream>>>(c2_w2, w2r,    256, 256, 0);
  k_wrefmt_bf16<<<(9*256*128+255)/256, 256, 0, stream>>>(cv_w1, wv1,    256, 128, 0);
  k_wrefmt_bf16<<<(9*128*128+255)/256, 256, 0, stream>>>(cv_w2, wv2,    128, 128, 0);

  // upsample + concat -> Xb (NHWC bf16)
  k_upcat<<<32768, 256, 0, stream>>>(x1, x2, Xb);

  // pass 1 (rows): xg = Xb @ Wih^T + b ; recurrent -> RT (transposed layout)
  k_xg_gemm<<<dim3(256, 8), 256, 0, stream>>>(Xb, wihc, biasc, XG);
  k_lstm_rec<<<dim3(16, 2), 256, 0, stream>>>(XG, Whh_f, Whh_b, RT);
  // pass 2 (cols): xg = RT @ Wih^T + b ; recurrent -> Sb (NHWC layout)
  k_xg_gemm<<<dim3(256, 8), 256, 0, stream>>>(RT, wihc, biasc, XG);
  k_lstm_rec<<<dim3(16, 2), 256, 0, stream>>>(XG, Whh_f, Whh_b, Sb);

  // x_site = double_conv(concat([S,S])) with folded first conv
  k_conv3_mfma<<<dim3(256,2), 256, 0, stream>>>(Sb, nullptr, w1f, c2_g1, c2_b1,
                                                nullptr, D1, 256, 256, 0);      // T1
  k_conv3_mfma<<<dim3(256,2), 256, 0, stream>>>(D1, nullptr, w2r, c2_g2, c2_b2,
                                                nullptr, D2, 256, 256, 0);      // XS
  // x = double_conv(concat([S, XS]))
  k_conv3_mfma<<<dim3(256,2), 256, 0, stream>>>(Sb, D2, w1full, c2_g1, c2_b1,
                                                nullptr, D2b, 512, 256, 0);     // T2
  k_conv3_mfma<<<dim3(256,2), 256, 0, stream>>>(D2b, nullptr, w2r, c2_g2, c2_b2,
                                                nullptr, D1, 256, 256, 0);      // Y
  // final double_conv (cv); last conv writes fp32 NCHW to d_out
  k_conv3_mfma<<<dim3(256,1), 256, 0, stream>>>(D1, nullptr, wv1, cv_g1, cv_b1,
                                                nullptr, D2, 256, 128, 0);      // Z
  k_conv3_mfma<<<dim3(256,1), 256, 0, stream>>>(D2, nullptr, wv2, cv_g2, cv_b2,
                                                (float*)d_out, nullptr, 128, 128, 1);
}

// Round 4
// 1016.664 us; speedup vs baseline: 7.1136x; 1.6325x over previous
//
#include <hip/hip_runtime.h>
#include <hip/hip_bf16.h>
#include <math.h>

typedef __bf16 bf16x8 __attribute__((ext_vector_type(8)));
typedef float  f32x4  __attribute__((ext_vector_type(4)));

__device__ __forceinline__ float sigm(float x)  { return 1.f/(1.f+__expf(-x)); }
__device__ __forceinline__ float tanh_f(float x){ return 2.f/(1.f+__expf(-2.f*x)) - 1.f; }
__device__ __forceinline__ float b2f(unsigned short u){
  unsigned int x = ((unsigned int)u) << 16; return __uint_as_float(x);
}
__device__ __forceinline__ unsigned short f2b(float v){
  __hip_bfloat16 h = __float2bfloat16(v); return *(unsigned short*)&h;
}
__device__ __forceinline__ void glds16(const void* g, void* l) {
  __builtin_amdgcn_global_load_lds(
      (const __attribute__((address_space(1))) unsigned int*)g,
      (__attribute__((address_space(3))) unsigned int*)l, 16, 0, 0);
}
__device__ __forceinline__ bf16x8 bzero() {
  bf16x8 v;
  #pragma unroll
  for (int i = 0; i < 8; ++i) v[i] = (__bf16)0.0f;
  return v;
}

// ---------------- upsample(2x, align_corners) + channel concat -> NHWC bf16 --------------
__global__ __launch_bounds__(256) void k_upcat(const float* __restrict__ x1,
                                               const float* __restrict__ x2,
                                               __hip_bfloat16* __restrict__ X0) {
  int idx = blockIdx.x*256 + threadIdx.x;
  int c = idx & 255;
  int w = (idx >> 8) & 63;
  int h = (idx >> 14) & 63;
  int n = idx >> 20;
  float v;
  if (c < 128) {
    v = x2[((n*128 + c)*64 + h)*64 + w];
  } else {
    int cc = c - 128;
    float py = (h*31.0f)/63.0f;
    int ly = (int)py; int hy = min(ly+1, 31); float fy = py - (float)ly;
    float px = (w*31.0f)/63.0f;
    int lx = (int)px; int hx = min(lx+1, 31); float fx = px - (float)lx;
    const float* p = x1 + (size_t)(n*128 + cc)*1024;
    float v00 = p[ly*32+lx], v01 = p[ly*32+hx];
    float v10 = p[hy*32+lx], v11 = p[hy*32+hx];
    v = (1.f-fy)*((1.f-fx)*v00 + fx*v01) + fy*((1.f-fx)*v10 + fx*v11);
  }
  X0[idx] = __float2bfloat16(v);
}

// ---------------- Wih concat -> bf16 [1024][256]; biasc[1024] = bih+bhh ------------------
__global__ __launch_bounds__(256) void k_wih_prep(
    const float* __restrict__ Wf, const float* __restrict__ Wb,
    const float* __restrict__ bif, const float* __restrict__ bhf,
    const float* __restrict__ bib, const float* __restrict__ bhb,
    __hip_bfloat16* __restrict__ wihc, float* __restrict__ biasc) {
  int idx = blockIdx.x*256 + threadIdx.x;     // 1024*256
  int n = idx >> 8, k = idx & 255;
  float v = (n < 512) ? Wf[n*256 + k] : Wb[(n-512)*256 + k];
  wihc[idx] = __float2bfloat16(v);
  if (idx < 1024) biasc[idx] = (idx < 512) ? bif[idx] + bhf[idx]
                                           : bib[idx-512] + bhb[idx-512];
}

// ---------------- xg GEMM: xg[dir][t][seq][gate] (fragment-swizzled bf16) ----------------
__global__ __launch_bounds__(256) void k_xg_gemm(
    const __hip_bfloat16* __restrict__ Xin,
    const __hip_bfloat16* __restrict__ Wihc,
    const float* __restrict__ biasc,
    __hip_bfloat16* __restrict__ xg) {
  __shared__ __align__(16) unsigned short sa[128][72];
  __shared__ __align__(16) unsigned short sw[128][72];
  int bx = blockIdx.x;                 // 256: t = bx>>2, seq0 = (bx&3)*128
  int t = bx >> 2, seq0 = (bx & 3) << 7;
  int n0 = blockIdx.y << 7;
  int tid = threadIdx.x, lane = tid & 63, wid = tid >> 6;
  int wm = wid >> 1, wn = wid & 1;
  int l15 = lane & 15, quad = lane >> 4;
  f32x4 acc[4][4];
  #pragma unroll
  for (int i = 0; i < 4; ++i)
    #pragma unroll
    for (int j = 0; j < 4; ++j) acc[i][j] = (f32x4){0.f,0.f,0.f,0.f};

  for (int k0 = 0; k0 < 256; k0 += 64) {
    __syncthreads();
    for (int idx = tid; idx < 2048; idx += 256) {
      int row = idx >> 4, c4 = (idx & 15) << 2;
      *(ushort4*)&sa[row][c4] = *(const ushort4*)((const unsigned short*)Xin +
          (size_t)((seq0 + row)*64 + t)*256 + k0 + c4);
      *(ushort4*)&sw[row][c4] = *(const ushort4*)((const unsigned short*)Wihc +
          (size_t)(n0 + row)*256 + k0 + c4);
    }
    __syncthreads();
    #pragma unroll
    for (int k32 = 0; k32 < 64; k32 += 32) {
      bf16x8 af[4], bfr[4];
      #pragma unroll
      for (int mt = 0; mt < 4; ++mt)
        af[mt] = *(const bf16x8*)&sa[wm*64 + mt*16 + l15][k32 + quad*8];
      #pragma unroll
      for (int nt = 0; nt < 4; ++nt)
        bfr[nt] = *(const bf16x8*)&sw[wn*64 + nt*16 + l15][k32 + quad*8];
      #pragma unroll
      for (int mt = 0; mt < 4; ++mt)
        #pragma unroll
        for (int nt = 0; nt < 4; ++nt)
          acc[mt][nt] = __builtin_amdgcn_mfma_f32_16x16x32_bf16(
              af[mt], bfr[nt], acc[mt][nt], 0, 0, 0);
    }
  }
  #pragma unroll
  for (int nt = 0; nt < 4; ++nt) {
    int n_g = n0 + wn*64 + nt*16;
    int dir = n_g >> 9;
    int gtile = (n_g & 511) >> 4;
    float bias = biasc[n_g + l15];
    #pragma unroll
    for (int mt = 0; mt < 4; ++mt) {
      int seq_tile = (seq0 + wm*64 + mt*16) >> 4;
      size_t base = ((size_t)(dir*64 + t)*1024 + seq_tile*32 + gtile)*256 + lane*4;
      f32x4 a = acc[mt][nt];
      ushort4 o;
      o.x = f2b(a[0] + bias); o.y = f2b(a[1] + bias);
      o.z = f2b(a[2] + bias); o.w = f2b(a[3] + bias);
      *(ushort4*)((unsigned short*)xg + base) = o;
    }
  }
}

// ---------------- recurrent LSTM core: 32 seqs/block, Whh in VGPRs, h in LDS -------------
__global__ __launch_bounds__(256, 1) void k_lstm_rec(
    const __hip_bfloat16* __restrict__ xg,
    const float* __restrict__ WhhF, const float* __restrict__ WhhB,
    __hip_bfloat16* __restrict__ out) {
  const int dir = blockIdx.y;
  const int sb  = blockIdx.x;               // seqs sb*32 .. +32
  const float* Whh = dir ? WhhB : WhhF;
  __shared__ __align__(16) unsigned short hs[32][136];   // [seq][unit], pad 128->136
  const int tid = threadIdx.x, lane = tid & 63, wv = tid >> 6;
  const int l15 = lane & 15, quad = lane >> 4;

  bf16x8 wf[4][2][4];
  #pragma unroll
  for (int g = 0; g < 4; ++g)
    #pragma unroll
    for (int ut = 0; ut < 2; ++ut) {
      int gate = g*128 + wv*32 + ut*16 + l15;
      #pragma unroll
      for (int kc = 0; kc < 4; ++kc) {
        const float* wp = Whh + (size_t)gate*128 + kc*32 + quad*8;
        float4 w0 = *(const float4*)wp;
        float4 w1 = *(const float4*)(wp + 4);
        bf16x8 f;
        f[0]=(__bf16)w0.x; f[1]=(__bf16)w0.y; f[2]=(__bf16)w0.z; f[3]=(__bf16)w0.w;
        f[4]=(__bf16)w1.x; f[5]=(__bf16)w1.y; f[6]=(__bf16)w1.z; f[7]=(__bf16)w1.w;
        wf[g][ut][kc] = f;
      }
    }
  for (int i = tid; i < 32*136; i += 256) ((unsigned short*)hs)[i] = 0;

  float cst[2][2][4];
  #pragma unroll
  for (int mt = 0; mt < 2; ++mt)
    #pragma unroll
    for (int ut = 0; ut < 2; ++ut)
      #pragma unroll
      for (int r = 0; r < 4; ++r) cst[mt][ut][r] = 0.f;

  const unsigned short* xbase = (const unsigned short*)xg +
      (size_t)dir*64*262144 + lane*4;
  ushort4 xv[2][4][2], xn[2][4][2];
  {
    int t0 = dir ? 63 : 0;
    #pragma unroll
    for (int mt = 0; mt < 2; ++mt)
      #pragma unroll
      for (int g = 0; g < 4; ++g)
        #pragma unroll
        for (int ut = 0; ut < 2; ++ut)
          xv[mt][g][ut] = *(const ushort4*)(xbase +
              ((size_t)t0*1024 + (sb*2 + mt)*32 + g*8 + wv*2 + ut)*256);
  }
  __syncthreads();

  for (int step = 0; step < 64; ++step) {
    int t = dir ? 63 - step : step;
    // prefetch next step's xg tiles early (covered by the MFMA block)
    {
      int ts = step + 1 < 64 ? step + 1 : 63;
      int tn = dir ? 63 - ts : ts;
      #pragma unroll
      for (int mt = 0; mt < 2; ++mt)
        #pragma unroll
        for (int g = 0; g < 4; ++g)
          #pragma unroll
          for (int ut = 0; ut < 2; ++ut)
            xn[mt][g][ut] = *(const ushort4*)(xbase +
                ((size_t)tn*1024 + (sb*2 + mt)*32 + g*8 + wv*2 + ut)*256);
    }
    bf16x8 af[2][4];
    #pragma unroll
    for (int mt = 0; mt < 2; ++mt)
      #pragma unroll
      for (int kc = 0; kc < 4; ++kc)
        af[mt][kc] = *(const bf16x8*)&hs[mt*16 + l15][kc*32 + quad*8];
    f32x4 acc[2][4][2];
    #pragma unroll
    for (int mt = 0; mt < 2; ++mt)
      #pragma unroll
      for (int g = 0; g < 4; ++g)
        #pragma unroll
        for (int ut = 0; ut < 2; ++ut) acc[mt][g][ut] = (f32x4){0.f,0.f,0.f,0.f};
    #pragma unroll
    for (int kc = 0; kc < 4; ++kc)
      #pragma unroll
      for (int mt = 0; mt < 2; ++mt)
        #pragma unroll
        for (int g = 0; g < 4; ++g)
          #pragma unroll
          for (int ut = 0; ut < 2; ++ut)
            acc[mt][g][ut] = __builtin_amdgcn_mfma_f32_16x16x32_bf16(
                af[mt][kc], wf[g][ut][kc], acc[mt][g][ut], 0, 0, 0);
    __syncthreads();                   // all waves done reading hs
    #pragma unroll
    for (int mt = 0; mt < 2; ++mt)
      #pragma unroll
      for (int ut = 0; ut < 2; ++ut) {
        const unsigned short* xi = (const unsigned short*)&xv[mt][0][ut];
        const unsigned short* xf = (const unsigned short*)&xv[mt][1][ut];
        const unsigned short* xgg= (const unsigned short*)&xv[mt][2][ut];
        const unsigned short* xo = (const unsigned short*)&xv[mt][3][ut];
        #pragma unroll
        for (int r = 0; r < 4; ++r) {
          float I = acc[mt][0][ut][r] + b2f(xi[r]);
          float F = acc[mt][1][ut][r] + b2f(xf[r]);
          float G = acc[mt][2][ut][r] + b2f(xgg[r]);
          float O = acc[mt][3][ut][r] + b2f(xo[r]);
          float cv = sigm(F)*cst[mt][ut][r] + sigm(I)*tanh_f(G);
          float hv = sigm(O)*tanh_f(cv);
          cst[mt][ut][r] = cv;
          unsigned short hb = f2b(hv);
          hs[mt*16 + quad*4 + r][wv*32 + ut*16 + l15] = hb;
          int s = sb*32 + mt*16 + quad*4 + r;
          size_t oa = (size_t)(((s >> 6)*64 + t)*64 + (s & 63))*256
                      + dir*128 + wv*32 + ut*16 + l15;
          ((unsigned short*)out)[oa] = hb;
        }
      }
    #pragma unroll
    for (int mt = 0; mt < 2; ++mt)
      #pragma unroll
      for (int g = 0; g < 4; ++g)
        #pragma unroll
        for (int ut = 0; ut < 2; ++ut) xv[mt][g][ut] = xn[mt][g][ut];
    __syncthreads();                   // hs ready for next step
  }
}

// ---------------- weight reformat OIHW fp32 -> (ky,kx,co,ci) bf16, optional fold ---------
__global__ __launch_bounds__(256) void k_wrefmt_bf16(const float* __restrict__ src,
                                                     __hip_bfloat16* __restrict__ dst,
                                                     int Ci, int Co, int fold) {
  int idx = blockIdx.x*256 + threadIdx.x;
  int total = 9*Ci*Co;
  if (idx >= total) return;
  int ci = idx % Ci;
  int co = (idx / Ci) % Co;
  int k  = idx / (Ci*Co);             // ky*3+kx
  int CiS = fold ? Ci*2 : Ci;
  float v = src[(size_t)(co*CiS + ci)*9 + k];
  if (fold) v += src[(size_t)(co*CiS + ci + Ci)*9 + k];
  dst[idx] = __float2bfloat16(v);
}

// ---------------- conv3x3 SAME + BN + ReLU, bf16 MFMA, async glds pipeline ---------------
// block: 2 h-rows x 64 w (M=128) x 128 co; 4 waves = 2x2 quadrants of 64x64.
// LDS: si[2][64][64] (no halo; w-edge taps zeroed per-lane), sw[3][128][64], both
// XOR-swizzled (16B chunk ^= row&7) so glds lane-order placement == balanced b128 reads.
// 2 barriers per (ky,ci0) stage; 96 MFMAs between barriers.
__global__ __launch_bounds__(256, 2) void k_conv3_v2(
    const __hip_bfloat16* __restrict__ inA, const __hip_bfloat16* __restrict__ inB,
    const __hip_bfloat16* __restrict__ wgt,
    const float* __restrict__ gam, const float* __restrict__ bet,
    float* __restrict__ outF, __hip_bfloat16* __restrict__ outB,
    int Cin, int Co, int nchw) {
  __shared__ __align__(16) unsigned short si[2][64][64];   // 16 KB
  __shared__ __align__(16) unsigned short sw[3][128][64];  // 48 KB  (total = 64 KB)
  int bx = blockIdx.x;
  int n  = bx >> 5;
  int h0 = (bx & 31) << 1;
  int co0 = blockIdx.y << 7;
  int tid = threadIdx.x;
  int lane = tid & 63;
  int wid  = tid >> 6;
  int wm = wid >> 1;                   // h-row of this wave's quadrant
  int wn = wid & 1;                    // co half
  int l15 = lane & 15, quad = lane >> 4;

  f32x4 acc[4][4];
  #pragma unroll
  for (int i = 0; i < 4; ++i)
    #pragma unroll
    for (int j = 0; j < 4; ++j) acc[i][j] = (f32x4){0.f,0.f,0.f,0.f};

  int cs = inB ? 256 : Cin;            // per-buffer channel stride
  for (int ky = 0; ky < 3; ++ky) {
    for (int ci0 = 0; ci0 < Cin; ci0 += 64) {
      const unsigned short* src = (const unsigned short*)inA; int cb = ci0;
      if (inB && ci0 >= 256) { src = (const unsigned short*)inB; cb = ci0 - 256; }
      __syncthreads();                 // previous si/sw fully consumed
      // ---- stage si: this wave covers row r=wid>>1, 32 pixels ----
      {
        int r = wid >> 1;
        int ih = h0 + r + ky - 1;
        int half = (wid & 1) << 5;     // pixel base 0 / 32
        if (ih >= 0 && ih <= 63) {
          const unsigned short* gsrc = src + (size_t)((n*64 + ih)*64)*cs + cb;
          int pl = lane >> 3, pc = lane & 7;
          #pragma unroll
          for (int q = 0; q < 4; ++q) {
            int iw = half + q*8 + pl;
            int lc = pc ^ (iw & 7);
            glds16(gsrc + (size_t)iw*cs + lc*8, &si[r][half + q*8][0]);
          }
        } else {
          uint4 z = {0,0,0,0};
          #pragma unroll
          for (int q = 0; q < 4; ++q)
            *(uint4*)(&si[r][half + q*8][0] + lane*8) = z;
        }
      }
      // ---- stage sw: all 3 kx slabs (48 segments of 1KB, 12 per wave) ----
      {
        int col = lane >> 3, pc = lane & 7;
        const unsigned short* wk = (const unsigned short*)wgt +
            (size_t)(ky*3*Co + co0)*Cin + ci0;
        #pragma unroll
        for (int j = 0; j < 12; ++j) {
          int s = wid + j*4;           // 0..47
          int kx = s >> 4, co8 = (s & 15) << 3;
          int co = co8 + col;
          int lc = pc ^ (co & 7);
          glds16(wk + (size_t)(kx*Co + co)*Cin + lc*8, &sw[kx][co8][0]);
        }
      }
      __syncthreads();                 // glds drained (vmcnt0 at barrier)
      // ---- compute: 3 kx x 2 k-steps x 16 MFMA ----
      #pragma unroll
      for (int kx = 0; kx < 3; ++kx) {
        #pragma unroll
        for (int k32 = 0; k32 < 2; ++k32) {
          bf16x8 af[4], bfr[4];
          #pragma unroll
          for (int mt = 0; mt < 4; ++mt) {
            int iw = mt*16 + l15 + kx - 1;
            int iwc = iw & 63;
            int pc = (k32*4 + quad) ^ (iwc & 7);
            af[mt] = *(const bf16x8*)&si[wm][iwc][pc*8];
            if ((kx == 0 && mt == 0 && l15 == 0) ||
                (kx == 2 && mt == 3 && l15 == 15))
              af[mt] = bzero();        // SAME-padding w-edge tap
          }
          #pragma unroll
          for (int nt = 0; nt < 4; ++nt) {
            int co = wn*64 + nt*16 + l15;
            int pc = (k32*4 + quad) ^ (co & 7);
            bfr[nt] = *(const bf16x8*)&sw[kx][co][pc*8];
          }
          #pragma unroll
          for (int mt = 0; mt < 4; ++mt)
            #pragma unroll
            for (int nt = 0; nt < 4; ++nt)
              acc[mt][nt] = __builtin_amdgcn_mfma_f32_16x16x32_bf16(
                  af[mt], bfr[nt], acc[mt][nt], 0, 0, 0);
        }
      }
    }
  }
  // epilogue: BN scale + ReLU; C/D layout col=lane&15, row=quad*4+reg
  const float kS = 0.9999950000374997f;   // 1/sqrt(1+1e-5)
  int h = h0 + wm;
  #pragma unroll
  for (int nt = 0; nt < 4; ++nt) {
    int co = co0 + wn*64 + nt*16 + l15;
    float scale = gam[co]*kS, bb = bet[co];
    #pragma unroll
    for (int mt = 0; mt < 4; ++mt) {
      f32x4 a = acc[mt][nt];
      #pragma unroll
      for (int r = 0; r < 4; ++r) {
        int w = mt*16 + quad*4 + r;
        float v = fmaf(a[r], scale, bb);
        v = v > 0.f ? v : 0.f;
        if (nchw) outF[(size_t)((n*Co + co)*64 + h)*64 + w] = v;
        else      outB[(size_t)((n*64 + h)*64 + w)*Co + co] = __float2bfloat16(v);
      }
    }
  }
}

extern "C" void kernel_launch(void* const* d_in, const int* in_sizes, int n_in,
                              void* d_out, int out_size, void* d_ws, size_t ws_size,
                              hipStream_t stream) {
  const float* x1    = (const float*)d_in[0];
  const float* x2    = (const float*)d_in[1];
  const float* Wih_f = (const float*)d_in[2];
  const float* Whh_f = (const float*)d_in[3];
  const float* bih_f = (const float*)d_in[4];
  const float* bhh_f = (const float*)d_in[5];
  const float* Wih_b = (const float*)d_in[6];
  const float* Whh_b = (const float*)d_in[7];
  const float* bih_b = (const float*)d_in[8];
  const float* bhh_b = (const float*)d_in[9];
  const float* c2_w1 = (const float*)d_in[10];
  const float* c2_g1 = (const float*)d_in[11];
  const float* c2_b1 = (const float*)d_in[12];
  const float* c2_w2 = (const float*)d_in[13];
  const float* c2_g2 = (const float*)d_in[14];
  const float* c2_b2 = (const float*)d_in[15];
  const float* cv_w1 = (const float*)d_in[16];
  const float* cv_g1 = (const float*)d_in[17];
  const float* cv_b1 = (const float*)d_in[18];
  const float* cv_w2 = (const float*)d_in[19];
  const float* cv_g2 = (const float*)d_in[20];
  const float* cv_b2 = (const float*)d_in[21];

  // ---- workspace layout (~107 MB, aliased) ----
  char* base = (char*)d_ws;
  const size_t SLOTB = 16777216ull;                 // bf16 activation slot
  __hip_bfloat16* Xb  = (__hip_bfloat16*)(base);
  __hip_bfloat16* Sb  = (__hip_bfloat16*)(base);
  __hip_bfloat16* XG  = (__hip_bfloat16*)(base + SLOTB);
  __hip_bfloat16* D2  = (__hip_bfloat16*)(base + SLOTB);
  __hip_bfloat16* D2b = (__hip_bfloat16*)(base + 2*SLOTB);
  __hip_bfloat16* RT  = (__hip_bfloat16*)(base + SLOTB + 67108864ull);
  __hip_bfloat16* D1  = RT;
  char* wq = base + SLOTB + 67108864ull + SLOTB;
  __hip_bfloat16* wihc  = (__hip_bfloat16*)wq;
  float*          biasc = (float*)(wq + 524288);
  char* cw = wq + 528384;
  __hip_bfloat16* w1f    = (__hip_bfloat16*)(cw);
  __hip_bfloat16* w1full = (__hip_bfloat16*)(cw + 1179648);
  __hip_bfloat16* w2r    = (__hip_bfloat16*)(cw + 3538944);
  __hip_bfloat16* wv1    = (__hip_bfloat16*)(cw + 4718592);
  __hip_bfloat16* wv2    = (__hip_bfloat16*)(cw + 5308416);

  // weight prep
  k_wih_prep<<<1024, 256, 0, stream>>>(Wih_f, Wih_b, bih_f, bhh_f, bih_b, bhh_b,
                                       wihc, biasc);
  k_wrefmt_bf16<<<(9*256*256+255)/256, 256, 0, stream>>>(c2_w1, w1f,    256, 256, 1);
  k_wrefmt_bf16<<<(9*512*256+255)/256, 256, 0, stream>>>(c2_w1, w1full, 512, 256, 0);
  k_wrefmt_bf16<<<(9*256*256+255)/256, 256, 0, stream>>>(c2_w2, w2r,    256, 256, 0);
  k_wrefmt_bf16<<<(9*256*128+255)/256, 256, 0, stream>>>(cv_w1, wv1,    256, 128, 0);
  k_wrefmt_bf16<<<(9*128*128+255)/256, 256, 0, stream>>>(cv_w2, wv2,    128, 128, 0);

  // upsample + concat -> Xb (NHWC bf16)
  k_upcat<<<32768, 256, 0, stream>>>(x1, x2, Xb);

  // pass 1 (rows): xg = Xb @ Wih^T + b ; recurrent -> RT (transposed layout)
  k_xg_gemm<<<dim3(256, 8), 256, 0, stream>>>(Xb, wihc, biasc, XG);
  k_lstm_rec<<<dim3(16, 2), 256, 0, stream>>>(XG, Whh_f, Whh_b, RT);
  // pass 2 (cols): xg = RT @ Wih^T + b ; recurrent -> Sb (NHWC layout)
  k_xg_gemm<<<dim3(256, 8), 256, 0, stream>>>(RT, wihc, biasc, XG);
  k_lstm_rec<<<dim3(16, 2), 256, 0, stream>>>(XG, Whh_f, Whh_b, Sb);

  // x_site = double_conv(concat([S,S])) with folded first conv
  k_conv3_v2<<<dim3(256,2), 256, 0, stream>>>(Sb, nullptr, w1f, c2_g1, c2_b1,
                                              nullptr, D1, 256, 256, 0);      // T1
  k_conv3_v2<<<dim3(256,2), 256, 0, stream>>>(D1, nullptr, w2r, c2_g2, c2_b2,
                                              nullptr, D2, 256, 256, 0);      // XS
  // x = double_conv(concat([S, XS]))
  k_conv3_v2<<<dim3(256,2), 256, 0, stream>>>(Sb, D2, w1full, c2_g1, c2_b1,
                                              nullptr, D2b, 512, 256, 0);     // T2
  k_conv3_v2<<<dim3(256,2), 256, 0, stream>>>(D2b, nullptr, w2r, c2_g2, c2_b2,
                                              nullptr, D1, 256, 256, 0);      // Y
  // final double_conv (cv); last conv writes fp32 NCHW to d_out
  k_conv3_v2<<<dim3(256,1), 256, 0, stream>>>(D1, nullptr, wv1, cv_g1, cv_b1,
                                              nullptr, D2, 256, 128, 0);      // Z
  k_conv3_v2<<<dim3(256,1), 256, 0, stream>>>(D2, nullptr, wv2, cv_g2, cv_b2,
                                              (float*)d_out, nullptr, 128, 128, 1);
}

// Round 5
// 768.800 us; speedup vs baseline: 9.4070x; 1.3224x over previous
//
#include <hip/hip_runtime.h>
#include <hip/hip_bf16.h>
#include <math.h>

typedef __bf16 bf16x8 __attribute__((ext_vector_type(8)));
typedef float  f32x4  __attribute__((ext_vector_type(4)));

__device__ __forceinline__ float sigm(float x)  { return 1.f/(1.f+__expf(-x)); }
__device__ __forceinline__ float tanh_f(float x){ return 2.f/(1.f+__expf(-2.f*x)) - 1.f; }
__device__ __forceinline__ float b2f(unsigned short u){
  unsigned int x = ((unsigned int)u) << 16; return __uint_as_float(x);
}
__device__ __forceinline__ unsigned short f2b(float v){
  __hip_bfloat16 h = __float2bfloat16(v); return *(unsigned short*)&h;
}
__device__ __forceinline__ void glds16(const void* g, void* l) {
  __builtin_amdgcn_global_load_lds(
      (const __attribute__((address_space(1))) unsigned int*)g,
      (__attribute__((address_space(3))) unsigned int*)l, 16, 0, 0);
}
__device__ __forceinline__ bf16x8 bzero() {
  bf16x8 v;
  #pragma unroll
  for (int i = 0; i < 8; ++i) v[i] = (__bf16)0.0f;
  return v;
}

// ---------------- upsample(2x, align_corners) + channel concat -> NHWC bf16 --------------
__global__ __launch_bounds__(256) void k_upcat(const float* __restrict__ x1,
                                               const float* __restrict__ x2,
                                               __hip_bfloat16* __restrict__ X0) {
  int idx = blockIdx.x*256 + threadIdx.x;
  int c = idx & 255;
  int w = (idx >> 8) & 63;
  int h = (idx >> 14) & 63;
  int n = idx >> 20;
  float v;
  if (c < 128) {
    v = x2[((n*128 + c)*64 + h)*64 + w];
  } else {
    int cc = c - 128;
    float py = (h*31.0f)/63.0f;
    int ly = (int)py; int hy = min(ly+1, 31); float fy = py - (float)ly;
    float px = (w*31.0f)/63.0f;
    int lx = (int)px; int hx = min(lx+1, 31); float fx = px - (float)lx;
    const float* p = x1 + (size_t)(n*128 + cc)*1024;
    float v00 = p[ly*32+lx], v01 = p[ly*32+hx];
    float v10 = p[hy*32+lx], v11 = p[hy*32+hx];
    v = (1.f-fy)*((1.f-fx)*v00 + fx*v01) + fy*((1.f-fx)*v10 + fx*v11);
  }
  X0[idx] = __float2bfloat16(v);
}

// ---------------- Wih concat -> bf16 [1024][256]; biasc[1024] = bih+bhh ------------------
__global__ __launch_bounds__(256) void k_wih_prep(
    const float* __restrict__ Wf, const float* __restrict__ Wb,
    const float* __restrict__ bif, const float* __restrict__ bhf,
    const float* __restrict__ bib, const float* __restrict__ bhb,
    __hip_bfloat16* __restrict__ wihc, float* __restrict__ biasc) {
  int idx = blockIdx.x*256 + threadIdx.x;     // 1024*256
  int n = idx >> 8, k = idx & 255;
  float v = (n < 512) ? Wf[n*256 + k] : Wb[(n-512)*256 + k];
  wihc[idx] = __float2bfloat16(v);
  if (idx < 1024) biasc[idx] = (idx < 512) ? bif[idx] + bhf[idx]
                                           : bib[idx-512] + bhb[idx-512];
}

// ---------------- xg GEMM: xg[dir][t][seq][gate] (fragment-swizzled bf16) ----------------
__global__ __launch_bounds__(256) void k_xg_gemm(
    const __hip_bfloat16* __restrict__ Xin,
    const __hip_bfloat16* __restrict__ Wihc,
    const float* __restrict__ biasc,
    __hip_bfloat16* __restrict__ xg) {
  __shared__ __align__(16) unsigned short sa[128][72];
  __shared__ __align__(16) unsigned short sw[128][72];
  int bx = blockIdx.x;                 // 256: t = bx>>2, seq0 = (bx&3)*128
  int t = bx >> 2, seq0 = (bx & 3) << 7;
  int n0 = blockIdx.y << 7;
  int tid = threadIdx.x, lane = tid & 63, wid = tid >> 6;
  int wm = wid >> 1, wn = wid & 1;
  int l15 = lane & 15, quad = lane >> 4;
  f32x4 acc[4][4];
  #pragma unroll
  for (int i = 0; i < 4; ++i)
    #pragma unroll
    for (int j = 0; j < 4; ++j) acc[i][j] = (f32x4){0.f,0.f,0.f,0.f};

  for (int k0 = 0; k0 < 256; k0 += 64) {
    __syncthreads();
    for (int idx = tid; idx < 2048; idx += 256) {
      int row = idx >> 4, c4 = (idx & 15) << 2;
      *(ushort4*)&sa[row][c4] = *(const ushort4*)((const unsigned short*)Xin +
          (size_t)((seq0 + row)*64 + t)*256 + k0 + c4);
      *(ushort4*)&sw[row][c4] = *(const ushort4*)((const unsigned short*)Wihc +
          (size_t)(n0 + row)*256 + k0 + c4);
    }
    __syncthreads();
    #pragma unroll
    for (int k32 = 0; k32 < 64; k32 += 32) {
      bf16x8 af[4], bfr[4];
      #pragma unroll
      for (int mt = 0; mt < 4; ++mt)
        af[mt] = *(const bf16x8*)&sa[wm*64 + mt*16 + l15][k32 + quad*8];
      #pragma unroll
      for (int nt = 0; nt < 4; ++nt)
        bfr[nt] = *(const bf16x8*)&sw[wn*64 + nt*16 + l15][k32 + quad*8];
      #pragma unroll
      for (int mt = 0; mt < 4; ++mt)
        #pragma unroll
        for (int nt = 0; nt < 4; ++nt)
          acc[mt][nt] = __builtin_amdgcn_mfma_f32_16x16x32_bf16(
              af[mt], bfr[nt], acc[mt][nt], 0, 0, 0);
    }
  }
  #pragma unroll
  for (int nt = 0; nt < 4; ++nt) {
    int n_g = n0 + wn*64 + nt*16;
    int dir = n_g >> 9;
    int gtile = (n_g & 511) >> 4;
    float bias = biasc[n_g + l15];
    #pragma unroll
    for (int mt = 0; mt < 4; ++mt) {
      int seq_tile = (seq0 + wm*64 + mt*16) >> 4;
      size_t base = ((size_t)(dir*64 + t)*1024 + seq_tile*32 + gtile)*256 + lane*4;
      f32x4 a = acc[mt][nt];
      ushort4 o;
      o.x = f2b(a[0] + bias); o.y = f2b(a[1] + bias);
      o.z = f2b(a[2] + bias); o.w = f2b(a[3] + bias);
      *(ushort4*)((unsigned short*)xg + base) = o;
    }
  }
}

// ---------------- recurrent LSTM core v2: 16 seqs/block, 64 blocks ----------------------
// grid (32, 2). Whh in VGPRs, h double-buffered in LDS (1 barrier/step),
// coalesced 16B h-stores from LDS. Out layout: ((b*64+t)*64 + s&63)*256 + dir*128 + u.
__global__ __launch_bounds__(256, 1) void k_lstm_rec(
    const __hip_bfloat16* __restrict__ xg,
    const float* __restrict__ WhhF, const float* __restrict__ WhhB,
    __hip_bfloat16* __restrict__ out) {
  const int dir = blockIdx.y;
  const int sb  = blockIdx.x;               // seqs sb*16 .. +16
  const float* Whh = dir ? WhhB : WhhF;
  __shared__ __align__(16) unsigned short hs[2][16][136];   // double-buffered
  const int tid = threadIdx.x, lane = tid & 63, wv = tid >> 6;
  const int l15 = lane & 15, quad = lane >> 4;

  // Whh fragments in registers: wf[g][ut][kc]; gate = g*128 + wv*32 + ut*16 + l15
  bf16x8 wf[4][2][4];
  #pragma unroll
  for (int g = 0; g < 4; ++g)
    #pragma unroll
    for (int ut = 0; ut < 2; ++ut) {
      int gate = g*128 + wv*32 + ut*16 + l15;
      #pragma unroll
      for (int kc = 0; kc < 4; ++kc) {
        const float* wp = Whh + (size_t)gate*128 + kc*32 + quad*8;
        float4 w0 = *(const float4*)wp;
        float4 w1 = *(const float4*)(wp + 4);
        bf16x8 f;
        f[0]=(__bf16)w0.x; f[1]=(__bf16)w0.y; f[2]=(__bf16)w0.z; f[3]=(__bf16)w0.w;
        f[4]=(__bf16)w1.x; f[5]=(__bf16)w1.y; f[6]=(__bf16)w1.z; f[7]=(__bf16)w1.w;
        wf[g][ut][kc] = f;
      }
    }
  for (int i = tid; i < 2*16*136; i += 256) ((unsigned short*)hs)[i] = 0;

  float cst[2][4];
  #pragma unroll
  for (int ut = 0; ut < 2; ++ut)
    #pragma unroll
    for (int r = 0; r < 4; ++r) cst[ut][r] = 0.f;

  const unsigned short* xbase = (const unsigned short*)xg +
      (size_t)dir*64*262144 + lane*4;
  ushort4 xv[4][2], xn[4][2];
  {
    int t0 = dir ? 63 : 0;
    #pragma unroll
    for (int g = 0; g < 4; ++g)
      #pragma unroll
      for (int ut = 0; ut < 2; ++ut)
        xv[g][ut] = *(const ushort4*)(xbase +
            ((size_t)t0*1024 + sb*32 + g*8 + wv*2 + ut)*256);
  }
  // coalesced-store mapping: thread -> (seq row ss, unit chunk u0)
  const int ss = tid >> 4, u0 = (tid & 15) << 3;
  unsigned short* obase = (unsigned short*)out +
      ((size_t)(sb >> 2)*4096 + (sb & 3)*16)*256 + dir*128;
  __syncthreads();

  for (int step = 0; step < 64; ++step) {
    int t = dir ? 63 - step : step;
    int p = step & 1;                 // read buffer
    // prefetch next step's xg tiles (consumed next iteration)
    {
      int tsn = step + 1 < 64 ? step + 1 : 63;
      int tn = dir ? 63 - tsn : tsn;
      #pragma unroll
      for (int g = 0; g < 4; ++g)
        #pragma unroll
        for (int ut = 0; ut < 2; ++ut)
          xn[g][ut] = *(const ushort4*)(xbase +
              ((size_t)tn*1024 + sb*32 + g*8 + wv*2 + ut)*256);
    }
    bf16x8 af[4];
    #pragma unroll
    for (int kc = 0; kc < 4; ++kc)
      af[kc] = *(const bf16x8*)&hs[p][l15][kc*32 + quad*8];
    f32x4 acc[4][2];
    #pragma unroll
    for (int g = 0; g < 4; ++g)
      #pragma unroll
      for (int ut = 0; ut < 2; ++ut) acc[g][ut] = (f32x4){0.f,0.f,0.f,0.f};
    #pragma unroll
    for (int kc = 0; kc < 4; ++kc)
      #pragma unroll
      for (int g = 0; g < 4; ++g)
        #pragma unroll
        for (int ut = 0; ut < 2; ++ut)
          acc[g][ut] = __builtin_amdgcn_mfma_f32_16x16x32_bf16(
              af[kc], wf[g][ut][kc], acc[g][ut], 0, 0, 0);
    // nonlinearity; write h(t) into the other buffer
    #pragma unroll
    for (int ut = 0; ut < 2; ++ut) {
      const unsigned short* xi = (const unsigned short*)&xv[0][ut];
      const unsigned short* xf = (const unsigned short*)&xv[1][ut];
      const unsigned short* xgg= (const unsigned short*)&xv[2][ut];
      const unsigned short* xo = (const unsigned short*)&xv[3][ut];
      #pragma unroll
      for (int r = 0; r < 4; ++r) {
        float I = acc[0][ut][r] + b2f(xi[r]);
        float F = acc[1][ut][r] + b2f(xf[r]);
        float G = acc[2][ut][r] + b2f(xgg[r]);
        float O = acc[3][ut][r] + b2f(xo[r]);
        float cv = sigm(F)*cst[ut][r] + sigm(I)*tanh_f(G);
        float hv = sigm(O)*tanh_f(cv);
        cst[ut][r] = cv;
        hs[1 - p][quad*4 + r][wv*32 + ut*16 + l15] = f2b(hv);
      }
    }
    __syncthreads();                   // h(t) visible to all waves
    // coalesced 16B store of h(t) from the just-written buffer
    {
      uint4 v = *(const uint4*)&hs[1 - p][ss][u0];
      *(uint4*)(obase + ((size_t)t*64 + ss)*256 + u0) = v;
    }
    #pragma unroll
    for (int g = 0; g < 4; ++g)
      #pragma unroll
      for (int ut = 0; ut < 2; ++ut) xv[g][ut] = xn[g][ut];
  }
}

// ---------------- weight reformat OIHW fp32 -> (ky,kx,co,ci) bf16, optional fold ---------
__global__ __launch_bounds__(256) void k_wrefmt_bf16(const float* __restrict__ src,
                                                     __hip_bfloat16* __restrict__ dst,
                                                     int Ci, int Co, int fold) {
  int idx = blockIdx.x*256 + threadIdx.x;
  int total = 9*Ci*Co;
  if (idx >= total) return;
  int ci = idx % Ci;
  int co = (idx / Ci) % Co;
  int k  = idx / (Ci*Co);             // ky*3+kx
  int CiS = fold ? Ci*2 : Ci;
  float v = src[(size_t)(co*CiS + ci)*9 + k];
  if (fold) v += src[(size_t)(co*CiS + ci + Ci)*9 + k];
  dst[idx] = __float2bfloat16(v);
}

// ---------------- conv3x3 SAME + BN + ReLU, bf16 MFMA, async glds pipeline ---------------
__global__ __launch_bounds__(256, 2) void k_conv3_v2(
    const __hip_bfloat16* __restrict__ inA, const __hip_bfloat16* __restrict__ inB,
    const __hip_bfloat16* __restrict__ wgt,
    const float* __restrict__ gam, const float* __restrict__ bet,
    float* __restrict__ outF, __hip_bfloat16* __restrict__ outB,
    int Cin, int Co, int nchw) {
  __shared__ __align__(16) unsigned short si[2][64][64];   // 16 KB
  __shared__ __align__(16) unsigned short sw[3][128][64];  // 48 KB
  int bx = blockIdx.x;
  int n  = bx >> 5;
  int h0 = (bx & 31) << 1;
  int co0 = blockIdx.y << 7;
  int tid = threadIdx.x;
  int lane = tid & 63;
  int wid  = tid >> 6;
  int wm = wid >> 1;
  int wn = wid & 1;
  int l15 = lane & 15, quad = lane >> 4;

  f32x4 acc[4][4];
  #pragma unroll
  for (int i = 0; i < 4; ++i)
    #pragma unroll
    for (int j = 0; j < 4; ++j) acc[i][j] = (f32x4){0.f,0.f,0.f,0.f};

  int cs = inB ? 256 : Cin;
  for (int ky = 0; ky < 3; ++ky) {
    for (int ci0 = 0; ci0 < Cin; ci0 += 64) {
      const unsigned short* src = (const unsigned short*)inA; int cb = ci0;
      if (inB && ci0 >= 256) { src = (const unsigned short*)inB; cb = ci0 - 256; }
      __syncthreads();
      {
        int r = wid >> 1;
        int ih = h0 + r + ky - 1;
        int half = (wid & 1) << 5;
        if (ih >= 0 && ih <= 63) {
          const unsigned short* gsrc = src + (size_t)((n*64 + ih)*64)*cs + cb;
          int pl = lane >> 3, pc = lane & 7;
          #pragma unroll
          for (int q = 0; q < 4; ++q) {
            int iw = half + q*8 + pl;
            int lc = pc ^ (iw & 7);
            glds16(gsrc + (size_t)iw*cs + lc*8, &si[r][half + q*8][0]);
          }
        } else {
          uint4 z = {0,0,0,0};
          #pragma unroll
          for (int q = 0; q < 4; ++q)
            *(uint4*)(&si[r][half + q*8][0] + lane*8) = z;
        }
      }
      {
        int col = lane >> 3, pc = lane & 7;
        const unsigned short* wk = (const unsigned short*)wgt +
            (size_t)(ky*3*Co + co0)*Cin + ci0;
        #pragma unroll
        for (int j = 0; j < 12; ++j) {
          int s = wid + j*4;
          int kx = s >> 4, co8 = (s & 15) << 3;
          int co = co8 + col;
          int lc = pc ^ (co & 7);
          glds16(wk + (size_t)(kx*Co + co)*Cin + lc*8, &sw[kx][co8][0]);
        }
      }
      __syncthreads();
      #pragma unroll
      for (int kx = 0; kx < 3; ++kx) {
        #pragma unroll
        for (int k32 = 0; k32 < 2; ++k32) {
          bf16x8 af[4], bfr[4];
          #pragma unroll
          for (int mt = 0; mt < 4; ++mt) {
            int iw = mt*16 + l15 + kx - 1;
            int iwc = iw & 63;
            int pc = (k32*4 + quad) ^ (iwc & 7);
            af[mt] = *(const bf16x8*)&si[wm][iwc][pc*8];
            if ((kx == 0 && mt == 0 && l15 == 0) ||
                (kx == 2 && mt == 3 && l15 == 15))
              af[mt] = bzero();
          }
          #pragma unroll
          for (int nt = 0; nt < 4; ++nt) {
            int co = wn*64 + nt*16 + l15;
            int pc = (k32*4 + quad) ^ (co & 7);
            bfr[nt] = *(const bf16x8*)&sw[kx][co][pc*8];
          }
          #pragma unroll
          for (int mt = 0; mt < 4; ++mt)
            #pragma unroll
            for (int nt = 0; nt < 4; ++nt)
              acc[mt][nt] = __builtin_amdgcn_mfma_f32_16x16x32_bf16(
                  af[mt], bfr[nt], acc[mt][nt], 0, 0, 0);
        }
      }
    }
  }
  const float kS = 0.9999950000374997f;   // 1/sqrt(1+1e-5)
  int h = h0 + wm;
  #pragma unroll
  for (int nt = 0; nt < 4; ++nt) {
    int co = co0 + wn*64 + nt*16 + l15;
    float scale = gam[co]*kS, bb = bet[co];
    #pragma unroll
    for (int mt = 0; mt < 4; ++mt) {
      f32x4 a = acc[mt][nt];
      #pragma unroll
      for (int r = 0; r < 4; ++r) {
        int w = mt*16 + quad*4 + r;
        float v = fmaf(a[r], scale, bb);
        v = v > 0.f ? v : 0.f;
        if (nchw) outF[(size_t)((n*Co + co)*64 + h)*64 + w] = v;
        else      outB[(size_t)((n*64 + h)*64 + w)*Co + co] = __float2bfloat16(v);
      }
    }
  }
}

extern "C" void kernel_launch(void* const* d_in, const int* in_sizes, int n_in,
                              void* d_out, int out_size, void* d_ws, size_t ws_size,
                              hipStream_t stream) {
  const float* x1    = (const float*)d_in[0];
  const float* x2    = (const float*)d_in[1];
  const float* Wih_f = (const float*)d_in[2];
  const float* Whh_f = (const float*)d_in[3];
  const float* bih_f = (const float*)d_in[4];
  const float* bhh_f = (const float*)d_in[5];
  const float* Wih_b = (const float*)d_in[6];
  const float* Whh_b = (const float*)d_in[7];
  const float* bih_b = (const float*)d_in[8];
  const float* bhh_b = (const float*)d_in[9];
  const float* c2_w1 = (const float*)d_in[10];
  const float* c2_g1 = (const float*)d_in[11];
  const float* c2_b1 = (const float*)d_in[12];
  const float* c2_w2 = (const float*)d_in[13];
  const float* c2_g2 = (const float*)d_in[14];
  const float* c2_b2 = (const float*)d_in[15];
  const float* cv_w1 = (const float*)d_in[16];
  const float* cv_g1 = (const float*)d_in[17];
  const float* cv_b1 = (const float*)d_in[18];
  const float* cv_w2 = (const float*)d_in[19];
  const float* cv_g2 = (const float*)d_in[20];
  const float* cv_b2 = (const float*)d_in[21];

  // ---- workspace layout (~107 MB, aliased) ----
  char* base = (char*)d_ws;
  const size_t SLOTB = 16777216ull;                 // bf16 activation slot
  __hip_bfloat16* Xb  = (__hip_bfloat16*)(base);
  __hip_bfloat16* Sb  = (__hip_bfloat16*)(base);
  __hip_bfloat16* XG  = (__hip_bfloat16*)(base + SLOTB);
  __hip_bfloat16* D2  = (__hip_bfloat16*)(base + SLOTB);
  __hip_bfloat16* D2b = (__hip_bfloat16*)(base + 2*SLOTB);
  __hip_bfloat16* RT  = (__hip_bfloat16*)(base + SLOTB + 67108864ull);
  __hip_bfloat16* D1  = RT;
  char* wq = base + SLOTB + 67108864ull + SLOTB;
  __hip_bfloat16* wihc  = (__hip_bfloat16*)wq;
  float*          biasc = (float*)(wq + 524288);
  char* cw = wq + 528384;
  __hip_bfloat16* w1f    = (__hip_bfloat16*)(cw);
  __hip_bfloat16* w1full = (__hip_bfloat16*)(cw + 1179648);
  __hip_bfloat16* w2r    = (__hip_bfloat16*)(cw + 3538944);
  __hip_bfloat16* wv1    = (__hip_bfloat16*)(cw + 4718592);
  __hip_bfloat16* wv2    = (__hip_bfloat16*)(cw + 5308416);

  // weight prep
  k_wih_prep<<<1024, 256, 0, stream>>>(Wih_f, Wih_b, bih_f, bhh_f, bih_b, bhh_b,
                                       wihc, biasc);
  k_wrefmt_bf16<<<(9*256*256+255)/256, 256, 0, stream>>>(c2_w1, w1f,    256, 256, 1);
  k_wrefmt_bf16<<<(9*512*256+255)/256, 256, 0, stream>>>(c2_w1, w1full, 512, 256, 0);
  k_wrefmt_bf16<<<(9*256*256+255)/256, 256, 0, stream>>>(c2_w2, w2r,    256, 256, 0);
  k_wrefmt_bf16<<<(9*256*128+255)/256, 256, 0, stream>>>(cv_w1, wv1,    256, 128, 0);
  k_wrefmt_bf16<<<(9*128*128+255)/256, 256, 0, stream>>>(cv_w2, wv2,    128, 128, 0);

  // upsample + concat -> Xb (NHWC bf16)
  k_upcat<<<32768, 256, 0, stream>>>(x1, x2, Xb);

  // pass 1 (rows): xg = Xb @ Wih^T + b ; recurrent -> RT (transposed layout)
  k_xg_gemm<<<dim3(256, 8), 256, 0, stream>>>(Xb, wihc, biasc, XG);
  k_lstm_rec<<<dim3(32, 2), 256, 0, stream>>>(XG, Whh_f, Whh_b, RT);
  // pass 2 (cols): xg = RT @ Wih^T + b ; recurrent -> Sb (NHWC layout)
  k_xg_gemm<<<dim3(256, 8), 256, 0, stream>>>(RT, wihc, biasc, XG);
  k_lstm_rec<<<dim3(32, 2), 256, 0, stream>>>(XG, Whh_f, Whh_b, Sb);

  // x_site = double_conv(concat([S,S])) with folded first conv
  k_conv3_v2<<<dim3(256,2), 256, 0, stream>>>(Sb, nullptr, w1f, c2_g1, c2_b1,
                                              nullptr, D1, 256, 256, 0);      // T1
  k_conv3_v2<<<dim3(256,2), 256, 0, stream>>>(D1, nullptr, w2r, c2_g2, c2_b2,
                                              nullptr, D2, 256, 256, 0);      // XS
  // x = double_conv(concat([S, XS]))
  k_conv3_v2<<<dim3(256,2), 256, 0, stream>>>(Sb, D2, w1full, c2_g1, c2_b1,
                                              nullptr, D2b, 512, 256, 0);     // T2
  k_conv3_v2<<<dim3(256,2), 256, 0, stream>>>(D2b, nullptr, w2r, c2_g2, c2_b2,
                                              nullptr, D1, 256, 256, 0);      // Y
  // final double_conv (cv); last conv writes fp32 NCHW to d_out
  k_conv3_v2<<<dim3(256,1), 256, 0, stream>>>(D1, nullptr, wv1, cv_g1, cv_b1,
                                              nullptr, D2, 256, 128, 0);      // Z
  k_conv3_v2<<<dim3(256,1), 256, 0, stream>>>(D2, nullptr, wv2, cv_g2, cv_b2,
                                              (float*)d_out, nullptr, 128, 128, 1);
}

// Round 6
// 662.460 us; speedup vs baseline: 10.9170x; 1.1605x over previous
//
#include <hip/hip_runtime.h>
#include <hip/hip_bf16.h>
#include <math.h>

typedef __bf16 bf16x8 __attribute__((ext_vector_type(8)));
typedef float  f32x4  __attribute__((ext_vector_type(4)));

__device__ __forceinline__ float sigm(float x)  { return 1.f/(1.f+__expf(-x)); }
__device__ __forceinline__ float tanh_f(float x){ return 2.f/(1.f+__expf(-2.f*x)) - 1.f; }
__device__ __forceinline__ float b2f(unsigned short u){
  unsigned int x = ((unsigned int)u) << 16; return __uint_as_float(x);
}
__device__ __forceinline__ unsigned short f2b(float v){
  __hip_bfloat16 h = __float2bfloat16(v); return *(unsigned short*)&h;
}
__device__ __forceinline__ void glds16(const void* g, void* l) {
  __builtin_amdgcn_global_load_lds(
      (const __attribute__((address_space(1))) unsigned int*)g,
      (__attribute__((address_space(3))) unsigned int*)l, 16, 0, 0);
}
__device__ __forceinline__ bf16x8 bzero() {
  bf16x8 v;
  #pragma unroll
  for (int i = 0; i < 8; ++i) v[i] = (__bf16)0.0f;
  return v;
}
// barrier with LDS-only ordering: skip the vmcnt(0) drain __syncthreads would emit.
// Safe here: global loads/stores around it are thread-private (no cross-thread dep).
__device__ __forceinline__ void barrier_lds() {
  asm volatile("s_waitcnt lgkmcnt(0)\n\ts_barrier" ::: "memory");
}

// ---------------- upsample(2x, align_corners) + channel concat -> NHWC bf16 --------------
__global__ __launch_bounds__(256) void k_upcat(const float* __restrict__ x1,
                                               const float* __restrict__ x2,
                                               __hip_bfloat16* __restrict__ X0) {
  int idx = blockIdx.x*256 + threadIdx.x;
  int c = idx & 255;
  int w = (idx >> 8) & 63;
  int h = (idx >> 14) & 63;
  int n = idx >> 20;
  float v;
  if (c < 128) {
    v = x2[((n*128 + c)*64 + h)*64 + w];
  } else {
    int cc = c - 128;
    float py = (h*31.0f)/63.0f;
    int ly = (int)py; int hy = min(ly+1, 31); float fy = py - (float)ly;
    float px = (w*31.0f)/63.0f;
    int lx = (int)px; int hx = min(lx+1, 31); float fx = px - (float)lx;
    const float* p = x1 + (size_t)(n*128 + cc)*1024;
    float v00 = p[ly*32+lx], v01 = p[ly*32+hx];
    float v10 = p[hy*32+lx], v11 = p[hy*32+hx];
    v = (1.f-fy)*((1.f-fx)*v00 + fx*v01) + fy*((1.f-fx)*v10 + fx*v11);
  }
  X0[idx] = __float2bfloat16(v);
}

// ---------------- Wih concat -> bf16 [1024][256]; biasc[1024] = bih+bhh ------------------
__global__ __launch_bounds__(256) void k_wih_prep(
    const float* __restrict__ Wf, const float* __restrict__ Wb,
    const float* __restrict__ bif, const float* __restrict__ bhf,
    const float* __restrict__ bib, const float* __restrict__ bhb,
    __hip_bfloat16* __restrict__ wihc, float* __restrict__ biasc) {
  int idx = blockIdx.x*256 + threadIdx.x;     // 1024*256
  int n = idx >> 8, k = idx & 255;
  float v = (n < 512) ? Wf[n*256 + k] : Wb[(n-512)*256 + k];
  wihc[idx] = __float2bfloat16(v);
  if (idx < 1024) biasc[idx] = (idx < 512) ? bif[idx] + bhf[idx]
                                           : bib[idx-512] + bhb[idx-512];
}

// ---------------- xg GEMM -> xg[dir][t][g][s][u] bf16 (planar, coalescable) --------------
__global__ __launch_bounds__(256) void k_xg_gemm(
    const __hip_bfloat16* __restrict__ Xin,
    const __hip_bfloat16* __restrict__ Wihc,
    const float* __restrict__ biasc,
    __hip_bfloat16* __restrict__ xg) {
  __shared__ __align__(16) unsigned short sa[128][72];
  __shared__ __align__(16) unsigned short sw[128][72];
  int bx = blockIdx.x;                 // 256: t = bx>>2, seq0 = (bx&3)*128
  int t = bx >> 2, seq0 = (bx & 3) << 7;
  int n0 = blockIdx.y << 7;
  int tid = threadIdx.x, lane = tid & 63, wid = tid >> 6;
  int wm = wid >> 1, wn = wid & 1;
  int l15 = lane & 15, quad = lane >> 4;
  f32x4 acc[4][4];
  #pragma unroll
  for (int i = 0; i < 4; ++i)
    #pragma unroll
    for (int j = 0; j < 4; ++j) acc[i][j] = (f32x4){0.f,0.f,0.f,0.f};

  for (int k0 = 0; k0 < 256; k0 += 64) {
    __syncthreads();
    for (int idx = tid; idx < 2048; idx += 256) {
      int row = idx >> 4, c4 = (idx & 15) << 2;
      *(ushort4*)&sa[row][c4] = *(const ushort4*)((const unsigned short*)Xin +
          (size_t)((seq0 + row)*64 + t)*256 + k0 + c4);
      *(ushort4*)&sw[row][c4] = *(const ushort4*)((const unsigned short*)Wihc +
          (size_t)(n0 + row)*256 + k0 + c4);
    }
    __syncthreads();
    #pragma unroll
    for (int k32 = 0; k32 < 64; k32 += 32) {
      bf16x8 af[4], bfr[4];
      #pragma unroll
      for (int mt = 0; mt < 4; ++mt)
        af[mt] = *(const bf16x8*)&sa[wm*64 + mt*16 + l15][k32 + quad*8];
      #pragma unroll
      for (int nt = 0; nt < 4; ++nt)
        bfr[nt] = *(const bf16x8*)&sw[wn*64 + nt*16 + l15][k32 + quad*8];
      #pragma unroll
      for (int mt = 0; mt < 4; ++mt)
        #pragma unroll
        for (int nt = 0; nt < 4; ++nt)
          acc[mt][nt] = __builtin_amdgcn_mfma_f32_16x16x32_bf16(
              af[mt], bfr[nt], acc[mt][nt], 0, 0, 0);
    }
  }
  // epilogue: + bias, bf16, planar store [dir][t][g][s][u]
  #pragma unroll
  for (int nt = 0; nt < 4; ++nt) {
    int cg = n0 + wn*64 + nt*16 + l15;        // gate col incl dir
    int dir = cg >> 9;
    int g   = (cg >> 7) & 3;
    int u   = cg & 127;
    float bias = biasc[cg];
    unsigned short* op = (unsigned short*)xg +
        (size_t)(((dir*64 + t)*4 + g)*512)*128 + u;
    #pragma unroll
    for (int mt = 0; mt < 4; ++mt) {
      int sbase = seq0 + wm*64 + mt*16 + quad*4;
      f32x4 a = acc[mt][nt];
      #pragma unroll
      for (int r = 0; r < 4; ++r)
        op[(size_t)(sbase + r)*128] = f2b(a[r] + bias);
    }
  }
}

// ---------------- recurrent LSTM core v3: 4 seqs/block, 256 blocks (full GPU) ------------
// grid (128, 2). Whh in VGPRs; h in LDS rows 0-3 (rows 4-15 zero); gate pre-activations
// redistributed via gv LDS so ALL lanes do nonlinearity (2 cells/thread).
__global__ __launch_bounds__(256, 1) void k_lstm_rec(
    const __hip_bfloat16* __restrict__ xg,
    const float* __restrict__ WhhF, const float* __restrict__ WhhB,
    __hip_bfloat16* __restrict__ out) {
  const int dir = blockIdx.y;
  const int sb  = blockIdx.x;               // seqs sb*4 .. +4
  const float* Whh = dir ? WhhB : WhhF;
  __shared__ __align__(16) unsigned short hs[16][136];   // rows 4-15 stay zero
  __shared__ __align__(16) float gv[4][128][4];          // [s][u][IFGO] 8KB
  const int tid = threadIdx.x, lane = tid & 63, wv = tid >> 6;
  const int l15 = lane & 15, quad = lane >> 4;

  // Whh fragments in registers: wf[g][ut][kc]; gate = g*128 + wv*32 + ut*16 + l15
  bf16x8 wf[4][2][4];
  #pragma unroll
  for (int g = 0; g < 4; ++g)
    #pragma unroll
    for (int ut = 0; ut < 2; ++ut) {
      int gate = g*128 + wv*32 + ut*16 + l15;
      #pragma unroll
      for (int kc = 0; kc < 4; ++kc) {
        const float* wp = Whh + (size_t)gate*128 + kc*32 + quad*8;
        float4 w0 = *(const float4*)wp;
        float4 w1 = *(const float4*)(wp + 4);
        bf16x8 f;
        f[0]=(__bf16)w0.x; f[1]=(__bf16)w0.y; f[2]=(__bf16)w0.z; f[3]=(__bf16)w0.w;
        f[4]=(__bf16)w1.x; f[5]=(__bf16)w1.y; f[6]=(__bf16)w1.z; f[7]=(__bf16)w1.w;
        wf[g][ut][kc] = f;
      }
    }
  for (int i = tid; i < 16*136; i += 256) ((unsigned short*)hs)[i] = 0;

  // cell mapping: thread handles cells (s0_, s0_+2) at unit u_
  const int u_  = tid & 127;
  const int s0_ = tid >> 7;
  float cst[2] = {0.f, 0.f};

  const unsigned short* xp = (const unsigned short*)xg +
      (size_t)dir*64*4*512*128;
  unsigned short xv[2][4], xn[2][4];
  // load xg for a given step into dst
  #define LDX(stp, dst)                                                    \
    {                                                                      \
      int ts_ = (stp) < 64 ? (stp) : 63;                                   \
      int t_  = dir ? 63 - ts_ : ts_;                                      \
      _Pragma("unroll")                                                    \
      for (int j_ = 0; j_ < 2; ++j_) {                                     \
        int s_ = s0_ + j_*2;                                               \
        _Pragma("unroll")                                                  \
        for (int g_ = 0; g_ < 4; ++g_)                                     \
          dst[j_][g_] = xp[(size_t)((t_*4 + g_)*512 + sb*4 + s_)*128 + u_];\
      }                                                                    \
    }
  LDX(0, xv);
  __syncthreads();                          // hs init visible

  for (int step = 0; step < 64; ++step) {
    int t = dir ? 63 - step : step;
    LDX(step + 1, xn);                      // prefetch (used next step)
    // A-frags from h(t-1)
    bf16x8 af[4];
    #pragma unroll
    for (int kc = 0; kc < 4; ++kc)
      af[kc] = *(const bf16x8*)&hs[l15][kc*32 + quad*8];
    f32x4 acc[4][2];
    #pragma unroll
    for (int g = 0; g < 4; ++g)
      #pragma unroll
      for (int ut = 0; ut < 2; ++ut) acc[g][ut] = (f32x4){0.f,0.f,0.f,0.f};
    #pragma unroll
    for (int kc = 0; kc < 4; ++kc)
      #pragma unroll
      for (int g = 0; g < 4; ++g)
        #pragma unroll
        for (int ut = 0; ut < 2; ++ut)
          acc[g][ut] = __builtin_amdgcn_mfma_f32_16x16x32_bf16(
              af[kc], wf[g][ut][kc], acc[g][ut], 0, 0, 0);
    // scatter valid rows (0-3 = quad0) to gv as float4{I,F,G,O}
    if (quad == 0) {
      #pragma unroll
      for (int ut = 0; ut < 2; ++ut) {
        int u = wv*32 + ut*16 + l15;
        #pragma unroll
        for (int r = 0; r < 4; ++r) {
          float4 q;
          q.x = acc[0][ut][r]; q.y = acc[1][ut][r];
          q.z = acc[2][ut][r]; q.w = acc[3][ut][r];
          *(float4*)&gv[r][u][0] = q;
        }
      }
    }
    barrier_lds();                          // gv ready
    // nonlinearity spread across all 256 threads: 2 cells each
    #pragma unroll
    for (int j = 0; j < 2; ++j) {
      int s = s0_ + j*2;
      float4 gq = *(const float4*)&gv[s][u_][0];
      float I = gq.x + b2f(xv[j][0]);
      float F = gq.y + b2f(xv[j][1]);
      float G = gq.z + b2f(xv[j][2]);
      float O = gq.w + b2f(xv[j][3]);
      float cv = sigm(F)*cst[j] + sigm(I)*tanh_f(G);
      float hv = sigm(O)*tanh_f(cv);
      cst[j] = cv;
      unsigned short hb = f2b(hv);
      hs[s][u_] = hb;
      int gs = sb*4 + s;
      ((unsigned short*)out)[(size_t)(((gs >> 6)*64 + t)*64 + (gs & 63))*256
                             + dir*128 + u_] = hb;
    }
    barrier_lds();                          // h(t) ready for next af read
    #pragma unroll
    for (int j = 0; j < 2; ++j)
      #pragma unroll
      for (int g = 0; g < 4; ++g) xv[j][g] = xn[j][g];
  }
  #undef LDX
}

// ---------------- weight reformat OIHW fp32 -> (ky,kx,co,ci) bf16, optional fold ---------
__global__ __launch_bounds__(256) void k_wrefmt_bf16(const float* __restrict__ src,
                                                     __hip_bfloat16* __restrict__ dst,
                                                     int Ci, int Co, int fold) {
  int idx = blockIdx.x*256 + threadIdx.x;
  int total = 9*Ci*Co;
  if (idx >= total) return;
  int ci = idx % Ci;
  int co = (idx / Ci) % Co;
  int k  = idx / (Ci*Co);             // ky*3+kx
  int CiS = fold ? Ci*2 : Ci;
  float v = src[(size_t)(co*CiS + ci)*9 + k];
  if (fold) v += src[(size_t)(co*CiS + ci + Ci)*9 + k];
  dst[idx] = __float2bfloat16(v);
}

// ---------------- conv3x3 SAME + BN + ReLU, bf16 MFMA, async glds pipeline ---------------
__global__ __launch_bounds__(256, 2) void k_conv3_v2(
    const __hip_bfloat16* __restrict__ inA, const __hip_bfloat16* __restrict__ inB,
    const __hip_bfloat16* __restrict__ wgt,
    const float* __restrict__ gam, const float* __restrict__ bet,
    float* __restrict__ outF, __hip_bfloat16* __restrict__ outB,
    int Cin, int Co, int nchw) {
  __shared__ __align__(16) unsigned short si[2][64][64];   // 16 KB
  __shared__ __align__(16) unsigned short sw[3][128][64];  // 48 KB
  int bx = blockIdx.x;
  int n  = bx >> 5;
  int h0 = (bx & 31) << 1;
  int co0 = blockIdx.y << 7;
  int tid = threadIdx.x;
  int lane = tid & 63;
  int wid  = tid >> 6;
  int wm = wid >> 1;
  int wn = wid & 1;
  int l15 = lane & 15, quad = lane >> 4;

  f32x4 acc[4][4];
  #pragma unroll
  for (int i = 0; i < 4; ++i)
    #pragma unroll
    for (int j = 0; j < 4; ++j) acc[i][j] = (f32x4){0.f,0.f,0.f,0.f};

  int cs = inB ? 256 : Cin;
  for (int ky = 0; ky < 3; ++ky) {
    for (int ci0 = 0; ci0 < Cin; ci0 += 64) {
      const unsigned short* src = (const unsigned short*)inA; int cb = ci0;
      if (inB && ci0 >= 256) { src = (const unsigned short*)inB; cb = ci0 - 256; }
      __syncthreads();
      {
        int r = wid >> 1;
        int ih = h0 + r + ky - 1;
        int half = (wid & 1) << 5;
        if (ih >= 0 && ih <= 63) {
          const unsigned short* gsrc = src + (size_t)((n*64 + ih)*64)*cs + cb;
          int pl = lane >> 3, pc = lane & 7;
          #pragma unroll
          for (int q = 0; q < 4; ++q) {
            int iw = half + q*8 + pl;
            int lc = pc ^ (iw & 7);
            glds16(gsrc + (size_t)iw*cs + lc*8, &si[r][half + q*8][0]);
          }
        } else {
          uint4 z = {0,0,0,0};
          #pragma unroll
          for (int q = 0; q < 4; ++q)
            *(uint4*)(&si[r][half + q*8][0] + lane*8) = z;
        }
      }
      {
        int col = lane >> 3, pc = lane & 7;
        const unsigned short* wk = (const unsigned short*)wgt +
            (size_t)(ky*3*Co + co0)*Cin + ci0;
        #pragma unroll
        for (int j = 0; j < 12; ++j) {
          int s = wid + j*4;
          int kx = s >> 4, co8 = (s & 15) << 3;
          int co = co8 + col;
          int lc = pc ^ (co & 7);
          glds16(wk + (size_t)(kx*Co + co)*Cin + lc*8, &sw[kx][co8][0]);
        }
      }
      __syncthreads();
      #pragma unroll
      for (int kx = 0; kx < 3; ++kx) {
        #pragma unroll
        for (int k32 = 0; k32 < 2; ++k32) {
          bf16x8 af[4], bfr[4];
          #pragma unroll
          for (int mt = 0; mt < 4; ++mt) {
            int iw = mt*16 + l15 + kx - 1;
            int iwc = iw & 63;
            int pc = (k32*4 + quad) ^ (iwc & 7);
            af[mt] = *(const bf16x8*)&si[wm][iwc][pc*8];
            if ((kx == 0 && mt == 0 && l15 == 0) ||
                (kx == 2 && mt == 3 && l15 == 15))
              af[mt] = bzero();
          }
          #pragma unroll
          for (int nt = 0; nt < 4; ++nt) {
            int co = wn*64 + nt*16 + l15;
            int pc = (k32*4 + quad) ^ (co & 7);
            bfr[nt] = *(const bf16x8*)&sw[kx][co][pc*8];
          }
          #pragma unroll
          for (int mt = 0; mt < 4; ++mt)
            #pragma unroll
            for (int nt = 0; nt < 4; ++nt)
              acc[mt][nt] = __builtin_amdgcn_mfma_f32_16x16x32_bf16(
                  af[mt], bfr[nt], acc[mt][nt], 0, 0, 0);
        }
      }
    }
  }
  const float kS = 0.9999950000374997f;   // 1/sqrt(1+1e-5)
  int h = h0 + wm;
  #pragma unroll
  for (int nt = 0; nt < 4; ++nt) {
    int co = co0 + wn*64 + nt*16 + l15;
    float scale = gam[co]*kS, bb = bet[co];
    #pragma unroll
    for (int mt = 0; mt < 4; ++mt) {
      f32x4 a = acc[mt][nt];
      #pragma unroll
      for (int r = 0; r < 4; ++r) {
        int w = mt*16 + quad*4 + r;
        float v = fmaf(a[r], scale, bb);
        v = v > 0.f ? v : 0.f;
        if (nchw) outF[(size_t)((n*Co + co)*64 + h)*64 + w] = v;
        else      outB[(size_t)((n*64 + h)*64 + w)*Co + co] = __float2bfloat16(v);
      }
    }
  }
}

extern "C" void kernel_launch(void* const* d_in, const int* in_sizes, int n_in,
                              void* d_out, int out_size, void* d_ws, size_t ws_size,
                              hipStream_t stream) {
  const float* x1    = (const float*)d_in[0];
  const float* x2    = (const float*)d_in[1];
  const float* Wih_f = (const float*)d_in[2];
  const float* Whh_f = (const float*)d_in[3];
  const float* bih_f = (const float*)d_in[4];
  const float* bhh_f = (const float*)d_in[5];
  const float* Wih_b = (const float*)d_in[6];
  const float* Whh_b = (const float*)d_in[7];
  const float* bih_b = (const float*)d_in[8];
  const float* bhh_b = (const float*)d_in[9];
  const float* c2_w1 = (const float*)d_in[10];
  const float* c2_g1 = (const float*)d_in[11];
  const float* c2_b1 = (const float*)d_in[12];
  const float* c2_w2 = (const float*)d_in[13];
  const float* c2_g2 = (const float*)d_in[14];
  const float* c2_b2 = (const float*)d_in[15];
  const float* cv_w1 = (const float*)d_in[16];
  const float* cv_g1 = (const float*)d_in[17];
  const float* cv_b1 = (const float*)d_in[18];
  const float* cv_w2 = (const float*)d_in[19];
  const float* cv_g2 = (const float*)d_in[20];
  const float* cv_b2 = (const float*)d_in[21];

  // ---- workspace layout (~107 MB, aliased) ----
  char* base = (char*)d_ws;
  const size_t SLOTB = 16777216ull;                 // bf16 activation slot
  __hip_bfloat16* Xb  = (__hip_bfloat16*)(base);
  __hip_bfloat16* Sb  = (__hip_bfloat16*)(base);
  __hip_bfloat16* XG  = (__hip_bfloat16*)(base + SLOTB);
  __hip_bfloat16* D2  = (__hip_bfloat16*)(base + SLOTB);
  __hip_bfloat16* D2b = (__hip_bfloat16*)(base + 2*SLOTB);
  __hip_bfloat16* RT  = (__hip_bfloat16*)(base + SLOTB + 67108864ull);
  __hip_bfloat16* D1  = RT;
  char* wq = base + SLOTB + 67108864ull + SLOTB;
  __hip_bfloat16* wihc  = (__hip_bfloat16*)wq;
  float*          biasc = (float*)(wq + 524288);
  char* cw = wq + 528384;
  __hip_bfloat16* w1f    = (__hip_bfloat16*)(cw);
  __hip_bfloat16* w1full = (__hip_bfloat16*)(cw + 1179648);
  __hip_bfloat16* w2r    = (__hip_bfloat16*)(cw + 3538944);
  __hip_bfloat16* wv1    = (__hip_bfloat16*)(cw + 4718592);
  __hip_bfloat16* wv2    = (__hip_bfloat16*)(cw + 5308416);

  // weight prep
  k_wih_prep<<<1024, 256, 0, stream>>>(Wih_f, Wih_b, bih_f, bhh_f, bih_b, bhh_b,
                                       wihc, biasc);
  k_wrefmt_bf16<<<(9*256*256+255)/256, 256, 0, stream>>>(c2_w1, w1f,    256, 256, 1);
  k_wrefmt_bf16<<<(9*512*256+255)/256, 256, 0, stream>>>(c2_w1, w1full, 512, 256, 0);
  k_wrefmt_bf16<<<(9*256*256+255)/256, 256, 0, stream>>>(c2_w2, w2r,    256, 256, 0);
  k_wrefmt_bf16<<<(9*256*128+255)/256, 256, 0, stream>>>(cv_w1, wv1,    256, 128, 0);
  k_wrefmt_bf16<<<(9*128*128+255)/256, 256, 0, stream>>>(cv_w2, wv2,    128, 128, 0);

  // upsample + concat -> Xb (NHWC bf16)
  k_upcat<<<32768, 256, 0, stream>>>(x1, x2, Xb);

  // pass 1 (rows): xg = Xb @ Wih^T + b ; recurrent -> RT (transposed layout)
  k_xg_gemm<<<dim3(256, 8), 256, 0, stream>>>(Xb, wihc, biasc, XG);
  k_lstm_rec<<<dim3(128, 2), 256, 0, stream>>>(XG, Whh_f, Whh_b, RT);
  // pass 2 (cols): xg = RT @ Wih^T + b ; recurrent -> Sb (NHWC layout)
  k_xg_gemm<<<dim3(256, 8), 256, 0, stream>>>(RT, wihc, biasc, XG);
  k_lstm_rec<<<dim3(128, 2), 256, 0, stream>>>(XG, Whh_f, Whh_b, Sb);

  // x_site = double_conv(concat([S,S])) with folded first conv
  k_conv3_v2<<<dim3(256,2), 256, 0, stream>>>(Sb, nullptr, w1f, c2_g1, c2_b1,
                                              nullptr, D1, 256, 256, 0);      // T1
  k_conv3_v2<<<dim3(256,2), 256, 0, stream>>>(D1, nullptr, w2r, c2_g2, c2_b2,
                                              nullptr, D2, 256, 256, 0);      // XS
  // x = double_conv(concat([S, XS]))
  k_conv3_v2<<<dim3(256,2), 256, 0, stream>>>(Sb, D2, w1full, c2_g1, c2_b1,
                                              nullptr, D2b, 512, 256, 0);     // T2
  k_conv3_v2<<<dim3(256,2), 256, 0, stream>>>(D2b, nullptr, w2r, c2_g2, c2_b2,
                                              nullptr, D1, 256, 256, 0);      // Y
  // final double_conv (cv); last conv writes fp32 NCHW to d_out
  k_conv3_v2<<<dim3(256,1), 256, 0, stream>>>(D1, nullptr, wv1, cv_g1, cv_b1,
                                              nullptr, D2, 256, 128, 0);      // Z
  k_conv3_v2<<<dim3(256,1), 256, 0, stream>>>(D2, nullptr, wv2, cv_g2, cv_b2,
                                              (float*)d_out, nullptr, 128, 128, 1);
}